// Round 4
// baseline (397.631 us; speedup 1.0000x reference)
//
#include <hip/hip_runtime.h>
#include <hip/hip_bf16.h>
#include <stdint.h>

#define B_ 2
#define S_ 2048
#define H_ 2048
#define NH_ 16
#define HD_ 128
#define M_ (B_*S_)

typedef __attribute__((ext_vector_type(8))) short short8_t;
typedef __attribute__((ext_vector_type(4))) float floatx4;
typedef __attribute__((ext_vector_type(16))) float floatx16;

__device__ __forceinline__ short f2bf(float f) {
  union { float f; uint32_t u; } x; x.f = f;
  const uint32_t u = x.u;
  return (short)((u + 0x7FFFu + ((u >> 16) & 1u)) >> 16);   // RNE
}

__device__ __forceinline__ void gload_lds16(const void* g, void* l) {
  __builtin_amdgcn_global_load_lds(
      (const __attribute__((address_space(1))) void*)g,
      (__attribute__((address_space(3))) void*)l, 16, 0, 0);
}

// ---------------------------------------------------------------- fused casts
__global__ __launch_bounds__(256)
void cast_all(const float* __restrict__ h,  const float* __restrict__ wq,
              const float* __restrict__ wk, const float* __restrict__ wv,
              const float* __restrict__ wo,
              short* __restrict__ hB,  short* __restrict__ wqB,
              short* __restrict__ wkB, short* __restrict__ wvB,
              short* __restrict__ woB) {
  const int blk = blockIdx.x;
  const float* src; short* dst; int off;
  if      (blk <  4096) { src = h;  dst = hB;  off = blk; }
  else if (blk <  6144) { src = wq; dst = wqB; off = blk - 4096; }
  else if (blk <  8192) { src = wk; dst = wkB; off = blk - 6144; }
  else if (blk < 10240) { src = wv; dst = wvB; off = blk - 8192; }
  else                  { src = wo; dst = woB; off = blk - 10240; }
  const int i = (off * 256 + threadIdx.x) * 8;
  typedef __attribute__((ext_vector_type(4))) float f4;
  const f4 a = *(const f4*)(src + i);
  const f4 b = *(const f4*)(src + i + 4);
  short8_t o;
  o[0] = f2bf(a[0]); o[1] = f2bf(a[1]); o[2] = f2bf(a[2]); o[3] = f2bf(a[3]);
  o[4] = f2bf(b[0]); o[5] = f2bf(b[1]); o[6] = f2bf(b[2]); o[7] = f2bf(b[3]);
  *(short8_t*)(dst + i) = o;
}

// ---------------------------------------------------------------- GEMM 256x256, BK=32, 2 phases/K-tile, 4-slot ring
// 8 waves (2M x 4N) of 128x64 output.  The R3 measurement isolated the
// bottleneck: 192 ds_read_b128/CU per K-tile-64 (~1600-2300 cy of DS-pipe
// time) is serialized against the 2048-cy MFMA window because each phase's
// reads are drained by lgkm(0) before its own burst.  This structure makes
// every DS read ride under an MFMA burst:
//   P0: [bar; lgkm(0) (aLo(u) landed); read b(u) x4; read aHi(u) x4;
//        stage A(u+3); lgkm(4) (b done, aHi IN FLIGHT under MFMA);
//        MFMA m-lo x16]
//   P1: [bar; lgkm(0) (aHi landed); vmcnt(6) (A/B(u+1) retired, counted);
//        prefetch aLo(u+1) x4 (hides under MFMA); stage B(u+3);
//        MFMA m-hi x16]
// Frag lifetimes are disjoint (aLo: P1(u-1)..P0(u); aHi,b: P0(u)..P1(u))
// -> no ping-pong, 48 frag VGPR.  Ring slot (u&3), staging distance 3 tiles
// (~2.5 phases ~ 1800 cy > 900 cy HBM latency).
//
// vmcnt ledger (2 stage-instr groups/phase: A@P0, B@P1, 2 gloads each):
//   issue seq: ..., A(u+1)@P0(u-2), B(u+1)@P1(u-2), A(u+2)@P0(u-1),
//   B(u+2)@P1(u-1), A(u+3)@P0(u), [vmcnt point @P1(u)] -> newest 6 =
//   {A(u+2),B(u+2),A(u+3)} -> vmcnt(6) retires A(u+1),B(u+1) exactly.
//   Slot-overwrite safety: stage(u+3) hits slot (u+3)&3 = (u-1)&3, whose
//   last reads (aHi/b(u-1)@P0(u-1)) are lgkm-retired before barrier@P1(u-1),
//   two barriers before the stage.  Tail: u >= NT-3 -> vmcnt(0) (stages for
//   u+3 stop; counted ledger no longer retires the needed group).
__device__ __forceinline__
void gemm256(const short* __restrict__ A, const short* __restrict__ Bm,
             const float* __restrict__ bias, short* __restrict__ C,
             const int m0, const int n0, const int N, const int K) {
  extern __shared__ short lds[];
  const int tid = threadIdx.x;
  const int w  = tid >> 6, ln = tid & 63;
  const int lr = ln >> 4,  lc = ln & 15;
  const int wm = (w >> 2) << 7;   // 0,128
  const int wn = (w & 3) << 6;    // 0,64,128,192

  // staging: 16 rows x 4 chunks per gload (R1-verified BK=32 geometry)
  const int srr = ln >> 2;                       // 0..15
  const int sgc = (ln & 3) ^ ((ln >> 3) & 3);    // pre-swizzled global chunk
  const short* aS0 = A  + (size_t)(m0 + w * 32 +      srr) * K + sgc * 8;
  const short* aS1 = A  + (size_t)(m0 + w * 32 + 16 + srr) * K + sgc * 8;
  const short* bS0 = Bm + (size_t)(n0 + w * 32 +      srr) * K + sgc * 8;
  const short* bS1 = Bm + (size_t)(n0 + w * 32 + 16 + srr) * K + sgc * 8;
  const int dA0 = w * 1024;          // wave's 32 LDS rows (shorts)
  const int dA1 = w * 1024 + 512;

#define SA_(u_) do { const int s_ = ((u_) & 3) * 16384;            \
    gload_lds16(aS0 + (size_t)(u_) * 32, &lds[s_ + dA0]);          \
    gload_lds16(aS1 + (size_t)(u_) * 32, &lds[s_ + dA1]); } while (0)
#define SB_(u_) do { const int s_ = ((u_) & 3) * 16384 + 8192;     \
    gload_lds16(bS0 + (size_t)(u_) * 32, &lds[s_ + dA0]);          \
    gload_lds16(bS1 + (size_t)(u_) * 32, &lds[s_ + dA1]); } while (0)

  // frag read offsets (R1-verified swizzle): row*32 + ((lr ^ ((lc>>1)&3))<<3)
  const int swz = (lr ^ ((lc >> 1) & 3)) << 3;
  const int aro = (wm + lc) * 32 + swz;          // + mf*512 (16 rows)
  const int bro = 8192 + (wn + lc) * 32 + swz;   // + nf*512

  floatx4 acc[8][4] = {};
  short8_t aLo[4], aHi[4], bf[4];

  const int NT = K >> 5;   // 64
  // prologue: stage tiles 0,1,2 (12 gloads); retire tile0; prefetch aLo(0)
  SA_(0); SB_(0); SA_(1); SB_(1); SA_(2); SB_(2);
  asm volatile("s_waitcnt vmcnt(8)" ::: "memory");
  __builtin_amdgcn_s_barrier();
#pragma unroll
  for (int mf = 0; mf < 4; ++mf)
    aLo[mf] = *(const short8_t*)&lds[aro + mf * 512];

  for (int u = 0; u < NT; ++u) {
    const int sb = (u & 3) * 16384;
    // ---------------- P0: MFMA m-lo (aLo . b)
    __builtin_amdgcn_s_barrier();
    asm volatile("s_waitcnt lgkmcnt(0)" ::: "memory");   // aLo(u) landed
    __builtin_amdgcn_sched_barrier(0);
#pragma unroll
    for (int nf = 0; nf < 4; ++nf)
      bf[nf] = *(const short8_t*)&lds[sb + bro + nf * 512];
    __builtin_amdgcn_sched_barrier(0);
#pragma unroll
    for (int mf = 0; mf < 4; ++mf)
      aHi[mf] = *(const short8_t*)&lds[sb + aro + 2048 + mf * 512];
    if (u + 3 < NT) SA_(u + 3);
    __builtin_amdgcn_sched_barrier(0);
    asm volatile("s_waitcnt lgkmcnt(4)" ::: "memory");   // b done; aHi flying
    __builtin_amdgcn_sched_barrier(0);
    __builtin_amdgcn_s_setprio(1);
#pragma unroll
    for (int mf = 0; mf < 4; ++mf)
#pragma unroll
      for (int nf = 0; nf < 4; ++nf)
        acc[mf][nf] = __builtin_amdgcn_mfma_f32_16x16x32_bf16(aLo[mf], bf[nf], acc[mf][nf], 0, 0, 0);
    __builtin_amdgcn_s_setprio(0);
    // ---------------- P1: MFMA m-hi (aHi . b), prefetch aLo(u+1)
    __builtin_amdgcn_s_barrier();
    asm volatile("s_waitcnt lgkmcnt(0)" ::: "memory");   // aHi(u) landed
    if (u < NT - 3) asm volatile("s_waitcnt vmcnt(6)" ::: "memory");
    else            asm volatile("s_waitcnt vmcnt(0)" ::: "memory");
    __builtin_amdgcn_sched_barrier(0);
    {
      const int un = (u + 1 < NT) ? u + 1 : u;           // branchless tail
      const int sbn = (un & 3) * 16384;
#pragma unroll
      for (int mf = 0; mf < 4; ++mf)
        aLo[mf] = *(const short8_t*)&lds[sbn + aro + mf * 512];
    }
    if (u + 3 < NT) SB_(u + 3);
    __builtin_amdgcn_sched_barrier(0);
    __builtin_amdgcn_s_setprio(1);
#pragma unroll
    for (int mf = 0; mf < 4; ++mf)
#pragma unroll
      for (int nf = 0; nf < 4; ++nf)
        acc[4 + mf][nf] = __builtin_amdgcn_mfma_f32_16x16x32_bf16(aHi[mf], bf[nf], acc[4 + mf][nf], 0, 0, 0);
    __builtin_amdgcn_s_setprio(0);
  }
#undef SA_
#undef SB_

#pragma unroll
  for (int mf = 0; mf < 8; ++mf) {
#pragma unroll
    for (int nf = 0; nf < 4; ++nf) {
      const int col = n0 + wn + nf * 16 + lc;
      const float bv = bias[col];
#pragma unroll
      for (int r = 0; r < 4; ++r) {
        const int row = m0 + wm + mf * 16 + lr * 4 + r;
        C[(size_t)row * N + col] = f2bf(acc[mf][nf][r] + bv);
      }
    }
  }
}

// fused QKV: 384 blocks = 16 m-tiles x (3 mats x 8 n-tiles).  XCD swizzle:
// XCD k owns 3 fixed B-panels (3 MB -> L2-resident) and walks mt 0..15 in
// lockstep with the other XCDs (shared A-panel -> single L3/HBM fetch).
__global__ __launch_bounds__(512, 2)
void gemm_qkv(const short* __restrict__ A,
              const short* __restrict__ W0, const short* __restrict__ W1, const short* __restrict__ W2,
              const float* __restrict__ b0, const float* __restrict__ b1, const float* __restrict__ b2,
              short* __restrict__ C0, short* __restrict__ C1, short* __restrict__ C2) {
  const int f   = blockIdx.y * 24 + blockIdx.x;   // dispatch-linear
  const int xcd = f & 7, s = f >> 3;              // s in 0..47
  const int xt  = xcd * 3 + (s >> 4);             // 3 xt per XCD
  const int mt  = s & 15;
  const int sel = xt >> 3, nt = xt & 7;
  const short* Bm   = sel == 0 ? W0 : (sel == 1 ? W1 : W2);
  const float* bias = sel == 0 ? b0 : (sel == 1 ? b1 : b2);
  short* C          = sel == 0 ? C0 : (sel == 1 ? C1 : C2);
  gemm256(A, Bm, bias, C, mt * 256, nt * 256, H_, H_);
}

// ---------------------------------------------------------------- GEMM core v2 (R1, kept for gemm_out)
// 8-wave 256x128 tile, BK=32, 4-deep LDS ring, counted vmcnt.
template<int MODE>
__device__ __forceinline__
void gemm_body256(const short* __restrict__ A, const short* __restrict__ Bm,
                  const float* __restrict__ bias, void* __restrict__ C,
                  const int m0, const int n0, const int N, const int K) {
  extern __shared__ short lds[];
  short* As = lds;            // 4 x 8192 shorts
  short* Bs = lds + 32768;    // 4 x 4096 shorts

  const int tid = threadIdx.x;
  const int w  = tid >> 6, ln = tid & 63;
  const int lr = ln >> 4,  lc = ln & 15;
  const int wm = (w >> 1) << 6;   // 0,64,128,192
  const int wn = (w & 1) << 6;    // 0,64

  const int srr = ln >> 2;                       // row within 16-row group
  const int sgc = (ln & 3) ^ ((ln >> 3) & 3);    // pre-swizzled global chunk

  const short* aSrc0 = A  + (size_t)(m0 + (w * 2 + 0) * 16 + srr) * K + sgc * 8;
  const short* aSrc1 = A  + (size_t)(m0 + (w * 2 + 1) * 16 + srr) * K + sgc * 8;
  const short* bSrc  = Bm + (size_t)(n0 +  w * 16          + srr) * K + sgc * 8;

  const int aDst0 = (w * 2 + 0) * 512;
  const int aDst1 = (w * 2 + 1) * 512;
  const int bDst  =  w * 512;

#define STAGE_(t_) do {                                      \
    const int bq_ = (t_) & 3; const int ko_ = (t_) * 32;     \
    gload_lds16(aSrc0 + ko_, &As[bq_ * 8192 + aDst0]);       \
    gload_lds16(aSrc1 + ko_, &As[bq_ * 8192 + aDst1]);       \
    gload_lds16(bSrc  + ko_, &Bs[bq_ * 4096 + bDst]);        \
  } while (0)

  STAGE_(0); STAGE_(1); STAGE_(2);

  floatx4 acc[4][4] = {};
  const int swz = (lr ^ ((lc >> 1) & 3)) << 3;
  const int aro = (wm + lc) * 32 + swz;
  const int bro = (wn + lc) * 32 + swz;

  asm volatile("s_waitcnt vmcnt(6)" ::: "memory");
  __builtin_amdgcn_s_barrier();

  const int NT = K >> 5;
  for (int t = 0; t < NT; ++t) {
    const int cb = t & 3;
    short8_t af[4], bfr[4];
#pragma unroll
    for (int i = 0; i < 4; ++i)
      af[i] = *(const short8_t*)&As[cb * 8192 + aro + i * 512];
#pragma unroll
    for (int j = 0; j < 4; ++j)
      bfr[j] = *(const short8_t*)&Bs[cb * 4096 + bro + j * 512];

    if (t + 3 < NT) STAGE_(t + 3);

    __builtin_amdgcn_s_barrier();
    asm volatile("s_waitcnt lgkmcnt(0)" ::: "memory");
    __builtin_amdgcn_sched_barrier(0);
    __builtin_amdgcn_s_setprio(1);
#pragma unroll
    for (int i = 0; i < 4; ++i)
#pragma unroll
      for (int j = 0; j < 4; ++j)
        acc[i][j] = __builtin_amdgcn_mfma_f32_16x16x32_bf16(af[i], bfr[j], acc[i][j], 0, 0, 0);
    __builtin_amdgcn_s_setprio(0);
    __builtin_amdgcn_sched_barrier(0);
    if (t < NT - 3)       asm volatile("s_waitcnt vmcnt(6)" ::: "memory");
    else if (t == NT - 3) asm volatile("s_waitcnt vmcnt(3)" ::: "memory");
    else if (t == NT - 2) asm volatile("s_waitcnt vmcnt(0)" ::: "memory");
    __builtin_amdgcn_s_barrier();
  }
#undef STAGE_

#pragma unroll
  for (int i = 0; i < 4; ++i) {
#pragma unroll
    for (int j = 0; j < 4; ++j) {
      const int col = n0 + wn + j * 16 + lc;
      const float bv = bias[col];
#pragma unroll
      for (int r = 0; r < 4; ++r) {
        const int row = m0 + wm + i * 16 + lr * 4 + r;
        const float v = acc[i][j][r] + bv;
        if (MODE == 1) ((float*)C)[(size_t)row * N + col] = v;
        else           ((short*)C)[(size_t)row * N + col] = f2bf(v);
      }
    }
  }
}

// grid (16, 16) = 256 blocks = 1 exact round
__global__ __launch_bounds__(512, 2)
void gemm_out(const short* __restrict__ A, const short* __restrict__ Bm,
              const float* __restrict__ bias, float* __restrict__ C) {
  gemm_body256<1>(A, Bm, bias, C, blockIdx.y * 256, blockIdx.x * 128, H_, H_);
}

// ---------------------------------------------------------------- V arrange (R5/R7-verified):
// row-major V[b*S+s][h*128+d] -> Vt[bh][kt][d][chunk c'=keychunk^(d&7)]
__global__ __launch_bounds__(256)
void arrange_v(const short* __restrict__ V, short* __restrict__ Vt) {
  __shared__ short T[64][72];
  const int b = blockIdx.z;
  const int s0 = blockIdx.x * 64, c0 = blockIdx.y * 64;
  const int t = threadIdx.x;
  const int r = t >> 3, c8 = (t & 7) * 8;
  const int kt = s0 >> 6;
#pragma unroll
  for (int p = 0; p < 2; ++p) {
    const int row = p * 32 + r;
    *(short8_t*)&T[row][c8] =
        *(const short8_t*)&V[(size_t)(b * S_ + s0 + row) * H_ + c0 + c8];
  }
  __syncthreads();
#pragma unroll
  for (int p = 0; p < 2; ++p) {
    const int row = p * 32 + r;
    const int gcol = c0 + row;
    const int hh = gcol >> 7, d = gcol & 127;
    short8_t o;
#pragma unroll
    for (int j = 0; j < 8; ++j) o[j] = T[c8 + j][row];
    const int chunk = (c8 >> 3) ^ (d & 7);
    *(short8_t*)&Vt[((((size_t)(b * 16 + hh) * 32 + kt) * 128 + d) << 6) + chunk * 8] = o;
  }
}

// ---------------------------------------------------------------- flash attention
// 256 threads = 4 waves x 32 q-rows, 32x32x16 MFMA, fixed-scale softmax
// (verified R2-R7).  S computed TRANSPOSED (S^T = K Q^T) so P lives per-lane
// by q; in-register half-wave shfl transpose feeds PV.  K/V double-buffered.
__global__ __launch_bounds__(256, 2)
void attention(const short* __restrict__ Q, const short* __restrict__ Kg,
               const short* __restrict__ Vt, short* __restrict__ O) {
  __shared__ short Ks[2][64 * 128];   // [key][c' = dchunk ^ (key&7)]
  __shared__ short Vs[2][128 * 64];   // [d][c' = keychunk ^ (d&7)]
  __shared__ float invLds[128];

  const int tid = threadIdx.x;
  const int wv = tid >> 6, ln = tid & 63;
  const int l32 = ln & 31, lh = ln >> 5;
  const int bh = blockIdx.y, b = bh >> 4, h = bh & 15;
  const int qw = blockIdx.x * 128 + wv * 32;

  const short* Qp  = Q  + ((size_t)(b * S_ + qw)) * H_ + h * HD_;
  const short* VtB = Vt + (size_t)bh * (S_ * HD_) + (size_t)wv * 2048 + ln * 8;

  const short* kp[4];
#pragma unroll
  for (int j = 0; j < 4; ++j) {
    const int key = wv * 16 + j * 4 + (ln >> 4);
    const int sc = (ln & 15) ^ (key & 7);
    kp[j] = Kg + (size_t)(b * S_ + key) * H_ + h * HD_ + sc * 8;
  }

  short8_t qf[8];
#pragma unroll
  for (int ksq = 0; ksq < 8; ++ksq)
    qf[ksq] = *(const short8_t*)&Qp[(size_t)l32 * H_ + ksq * 16 + lh * 8];

  floatx16 oacc[4] = {};
  float lsum = 0.f;
  const float csc = 0.08838834764831845f * 1.4426950408889634f;

#pragma unroll
  for (int j = 0; j < 4; ++j)
    gload_lds16(kp[j], &Ks[0][(wv * 16 + j * 4) * 128]);
#pragma unroll
  for (int j = 0; j < 4; ++j)
    gload_lds16(VtB + j * 512, &Vs[0][wv * 2048 + j * 512]);

  for (int kt = 0; kt < S_ / 64; ++kt) {
    const int cur = kt & 1;
    __syncthreads();

    if (kt + 1 < S_ / 64) {
      const size_t kadv = (size_t)(kt + 1) * 64 * H_;
#pragma unroll
      for (int j = 0; j < 4; ++j)
        gload_lds16(kp[j] + kadv, &Ks[cur ^ 1][(wv * 16 + j * 4) * 128]);
#pragma unroll
      for (int j = 0; j < 4; ++j)
        gload_lds16(VtB + (size_t)(kt + 1) * 8192 + j * 512, &Vs[cur ^ 1][wv * 2048 + j * 512]);
    }

    floatx16 sacc[2] = {};
#pragma unroll
    for (int kh = 0; kh < 2; ++kh) {
      const int key = kh * 32 + l32;
      const int swk = (key & 7) * 8;
#pragma unroll
      for (int ksq = 0; ksq < 8; ++ksq) {
        const short8_t kf =
            *(const short8_t*)&Ks[cur][key * 128 + (((ksq * 2 + lh) * 8) ^ swk)];
        sacc[kh] = __builtin_amdgcn_mfma_f32_32x32x16_bf16(kf, qf[ksq], sacc[kh], 0, 0, 0);
      }
    }

    int pfr[4][4];
#pragma unroll
    for (int kh = 0; kh < 2; ++kh) {
      uint32_t P[8];
#pragma unroll
      for (int i = 0; i < 8; ++i) {
        const uint32_t u0 = __float_as_uint(exp2f(sacc[kh][2 * i] * csc));
        const uint32_t u1 = __float_as_uint(exp2f(sacc[kh][2 * i + 1] * csc));
        lsum += __uint_as_float(u0 & 0xffff0000u) + __uint_as_float(u1 & 0xffff0000u);
        P[i] = (u0 >> 16) | (u1 & 0xffff0000u);
      }
#pragma unroll
      for (int t = 0; t < 2; ++t)
#pragma unroll
        for (int j = 0; j < 2; ++j) {
          const int a = (int)P[t * 4 + j], bb = (int)P[t * 4 + j + 2];
          const int as = __shfl_xor(a, 32), bs = __shfl_xor(bb, 32);
          pfr[kh * 2 + t][j]     = lh ? bs : a;
          pfr[kh * 2 + t][j + 2] = lh ? bb : as;
        }
    }

#pragma unroll
    for (int kf = 0; kf < 4; ++kf) {
      union { int i[4]; short8_t s; } pu;
#pragma unroll
      for (int j = 0; j < 4; ++j) pu.i[j] = pfr[kf][j];
#pragma unroll
      for (int dt = 0; dt < 4; ++dt) {
        const int d = dt * 32 + l32;
        const short8_t vf =
            *(const short8_t*)&Vs[cur][d * 64 + (((kf * 2 + lh) * 8) ^ ((d & 7) * 8))];
        oacc[dt] = __builtin_amdgcn_mfma_f32_32x32x16_bf16(pu.s, vf, oacc[dt], 0, 0, 0);
      }
    }
  }

  const float l = lsum + __shfl_xor(lsum, 32);
  invLds[wv * 32 + l32] = 1.0f / l;
  float inv[16];
#pragma unroll
  for (int r = 0; r < 16; ++r)
    inv[r] = invLds[wv * 32 + (r & 3) + 8 * (r >> 2) + 4 * lh];
  short* Op = O + ((size_t)(b * S_ + qw)) * H_ + h * HD_;
#pragma unroll
  for (int dt = 0; dt < 4; ++dt)
#pragma unroll
    for (int r = 0; r < 16; ++r) {
      const int rowl = (r & 3) + 8 * (r >> 2) + 4 * lh;
      Op[(size_t)rowl * H_ + dt * 32 + l32] = f2bf(oacc[dt][r] * inv[r]);
    }
}

// ---------------------------------------------------------------- launch
extern "C" void kernel_launch(void* const* d_in, const int* in_sizes, int n_in,
                              void* d_out, int out_size, void* d_ws, size_t ws_size,
                              hipStream_t stream) {
  const float* hidden = (const float*)d_in[0];
  const float* Wq = (const float*)d_in[1];
  const float* bq = (const float*)d_in[2];
  const float* Wk = (const float*)d_in[3];
  const float* bk = (const float*)d_in[4];
  const float* Wv = (const float*)d_in[5];
  const float* bv = (const float*)d_in[6];
  const float* Wo = (const float*)d_in[7];
  const float* bo = (const float*)d_in[8];
  float* out = (float*)d_out;

  char* ws = (char*)d_ws;
  short* hB  = (short*)(ws);                       // 16 MB
  short* WqB = (short*)(ws + (16u << 20));         //  8 MB each
  short* WkB = (short*)(ws + (24u << 20));
  short* WvB = (short*)(ws + (32u << 20));
  short* WoB = (short*)(ws + (40u << 20));
  short* Qb  = (short*)(ws + (48u << 20));         // 16 MB each
  short* Kb  = (short*)(ws + (64u << 20));         // K row-major
  short* Vb  = (short*)(ws + (80u << 20));         // V row-major
  short* Vtb = (short*)(ws + (96u << 20));         // V arranged
  short* Ob  = (short*)(ws + (112u << 20));

  constexpr int QKV_LDS = 4 * 16384 * 2;                // 128 KiB (4-slot ring)
  constexpr int OUT_LDS = (4 * 8192 + 4 * 4096) * 2;    // 96 KiB
  static int lds_set = 0;
  if (!lds_set) {
    lds_set = 1;
    (void)hipFuncSetAttribute((const void*)gemm_qkv,
        hipFuncAttributeMaxDynamicSharedMemorySize, QKV_LDS);
    (void)hipFuncSetAttribute((const void*)gemm_out,
        hipFuncAttributeMaxDynamicSharedMemorySize, OUT_LDS);
  }

  cast_all<<<12288, 256, 0, stream>>>(hidden, Wq, Wk, Wv, Wo, hB, WqB, WkB, WvB, WoB);

  gemm_qkv<<<dim3(24, 16), 512, QKV_LDS, stream>>>(hB, WqB, WkB, WvB, bq, bk, bv, Qb, Kb, Vb);

  arrange_v<<<dim3(S_ / 64, H_ / 64, B_), 256, 0, stream>>>(Vb, Vtb);

  attention<<<dim3(S_ / 128, B_ * NH_), 256, 0, stream>>>(Qb, Kb, Vtb, Ob);

  gemm_out<<<dim3(16, 16), 512, OUT_LDS, stream>>>(Ob, WoB, bo, out);
}

// Round 5
// 395.936 us; speedup vs baseline: 1.0043x; 1.0043x over previous
//
#include <hip/hip_runtime.h>
#include <hip/hip_bf16.h>
#include <stdint.h>

#define B_ 2
#define S_ 2048
#define H_ 2048
#define NH_ 16
#define HD_ 128
#define M_ (B_*S_)

typedef __attribute__((ext_vector_type(8))) short short8_t;
typedef __attribute__((ext_vector_type(4))) float floatx4;
typedef __attribute__((ext_vector_type(16))) float floatx16;

__device__ __forceinline__ short f2bf(float f) {
  union { float f; uint32_t u; } x; x.f = f;
  const uint32_t u = x.u;
  return (short)((u + 0x7FFFu + ((u >> 16) & 1u)) >> 16);   // RNE
}

__device__ __forceinline__ void gload_lds16(const void* g, void* l) {
  __builtin_amdgcn_global_load_lds(
      (const __attribute__((address_space(1))) void*)g,
      (__attribute__((address_space(3))) void*)l, 16, 0, 0);
}

// ---------------------------------------------------------------- fused casts
__global__ __launch_bounds__(256)
void cast_all(const float* __restrict__ h,  const float* __restrict__ wq,
              const float* __restrict__ wk, const float* __restrict__ wv,
              const float* __restrict__ wo,
              short* __restrict__ hB,  short* __restrict__ wqB,
              short* __restrict__ wkB, short* __restrict__ wvB,
              short* __restrict__ woB) {
  const int blk = blockIdx.x;
  const float* src; short* dst; int off;
  if      (blk <  4096) { src = h;  dst = hB;  off = blk; }
  else if (blk <  6144) { src = wq; dst = wqB; off = blk - 4096; }
  else if (blk <  8192) { src = wk; dst = wkB; off = blk - 6144; }
  else if (blk < 10240) { src = wv; dst = wvB; off = blk - 8192; }
  else                  { src = wo; dst = woB; off = blk - 10240; }
  const int i = (off * 256 + threadIdx.x) * 8;
  typedef __attribute__((ext_vector_type(4))) float f4;
  const f4 a = *(const f4*)(src + i);
  const f4 b = *(const f4*)(src + i + 4);
  short8_t o;
  o[0] = f2bf(a[0]); o[1] = f2bf(a[1]); o[2] = f2bf(a[2]); o[3] = f2bf(a[3]);
  o[4] = f2bf(b[0]); o[5] = f2bf(b[1]); o[6] = f2bf(b[2]); o[7] = f2bf(b[3]);
  *(short8_t*)(dst + i) = o;
}

// ---------------------------------------------------------------- GEMM 256x256, 4 phases/K-tile, ONE barrier/phase
// (R3 winner, 111.6 us, reverted verbatim.)  8 waves (2M x 4N) of 128x64
// output.  BK=64, double-buffered 128 KiB LDS.  One barrier per phase
// (before MFMA): a wave finishing its MFMA burst immediately issues the next
// phase's ds_reads/stages while other waves still MFMA.
//
// Hazard ledger: see R3 notes.  vmcnt(6) before barrier-P3(u); tail vmcnt(0).
__device__ __forceinline__
void gemm256(const short* __restrict__ A, const short* __restrict__ Bm,
             const float* __restrict__ bias, short* __restrict__ C,
             const int m0, const int n0, const int N, const int K) {
  extern __shared__ short lds[];
  const int tid = threadIdx.x;
  const int w  = tid >> 6, ln = tid & 63;
  const int lr = ln >> 4,  lc = ln & 15;
  const int wm = (w >> 2) << 7;   // 0,128
  const int wn = (w & 3) << 6;    // 0,64,128,192

  const int srow = ln >> 3;                 // 0..7
  const int schk = (ln & 7) ^ srow;         // pre-swizzled global chunk
  const short* aS = A  + (size_t)(m0 + w * 16 + srow) * K + schk * 8;
  const short* bS = Bm + (size_t)(n0 + w * 16 + srow) * K + schk * 8;
  const int dA = (w * 16) * 64;             // wave's dest rows (shorts)

#define SA_LO(u_) do { const int q_ = ((u_) & 1) * 32768;                    \
    gload_lds16(aS + (u_) * 64,                    &lds[q_ + dA]);           \
    gload_lds16(aS + (u_) * 64 + (size_t)8 * K,    &lds[q_ + dA + 512]); } while (0)
#define SA_HI(u_) do { const int q_ = ((u_) & 1) * 32768;                    \
    gload_lds16(aS + (u_) * 64 + (size_t)128 * K,  &lds[q_ + 8192 + dA]);    \
    gload_lds16(aS + (u_) * 64 + (size_t)136 * K,  &lds[q_ + 8192 + dA + 512]); } while (0)
#define SB_LO(u_) do { const int q_ = ((u_) & 1) * 32768;                    \
    gload_lds16(bS + (u_) * 64,                    &lds[q_ + 16384 + dA]);   \
    gload_lds16(bS + (u_) * 64 + (size_t)8 * K,    &lds[q_ + 16384 + dA + 512]); } while (0)
#define SB_HI(u_) do { const int q_ = ((u_) & 1) * 32768;                    \
    gload_lds16(bS + (u_) * 64 + (size_t)128 * K,  &lds[q_ + 24576 + dA]);   \
    gload_lds16(bS + (u_) * 64 + (size_t)136 * K,  &lds[q_ + 24576 + dA + 512]); } while (0)

  const int fsw = (lc & 7) << 3;
  const int k0o = (lr * 8) ^ fsw;
  const int k1o = (32 + lr * 8) ^ fsw;
  const int aro = (wm + lc) * 64;           // + half*4096 + mf*1024
  const int bro = 16384 + (wn + lc) * 64;   // + nf*1024

  floatx4 acc[8][4] = {};
  short8_t af[8], b0f[4], b1f[4];

  const int NT = K >> 6;   // 32
  SA_LO(0); SA_HI(0); SB_LO(0); SB_HI(0);
  SA_LO(1); SB_LO(1); SB_HI(1);
  asm volatile("s_waitcnt vmcnt(6)" ::: "memory");   // tile0 landed
  __builtin_amdgcn_s_barrier();

  for (int u = 0; u < NT; ++u) {
    const int Bb = (u & 1) * 32768;
    // -------- P0: read A0 + B0, stage A-hi(u+1); MFMA (m0, n0/n1)
#pragma unroll
    for (int mf = 0; mf < 4; ++mf) {
      af[mf * 2]     = *(const short8_t*)&lds[Bb + aro + mf * 1024 + k0o];
      af[mf * 2 + 1] = *(const short8_t*)&lds[Bb + aro + mf * 1024 + k1o];
    }
#pragma unroll
    for (int nf = 0; nf < 2; ++nf) {
      b0f[nf * 2]     = *(const short8_t*)&lds[Bb + bro + nf * 1024 + k0o];
      b0f[nf * 2 + 1] = *(const short8_t*)&lds[Bb + bro + nf * 1024 + k1o];
    }
    if (u + 1 < NT) SA_HI(u + 1);
    __builtin_amdgcn_sched_barrier(0);
    __builtin_amdgcn_s_barrier();
    asm volatile("s_waitcnt lgkmcnt(0)" ::: "memory");
    __builtin_amdgcn_sched_barrier(0);
    __builtin_amdgcn_s_setprio(1);
#pragma unroll
    for (int mf = 0; mf < 4; ++mf)
#pragma unroll
      for (int nf = 0; nf < 2; ++nf) {
        acc[mf][nf] = __builtin_amdgcn_mfma_f32_16x16x32_bf16(af[mf*2],   b0f[nf*2],   acc[mf][nf], 0, 0, 0);
        acc[mf][nf] = __builtin_amdgcn_mfma_f32_16x16x32_bf16(af[mf*2+1], b0f[nf*2+1], acc[mf][nf], 0, 0, 0);
      }
    __builtin_amdgcn_s_setprio(0);
    // -------- P1: read B1; MFMA (m0, n2/n3)
#pragma unroll
    for (int nf = 0; nf < 2; ++nf) {
      b1f[nf * 2]     = *(const short8_t*)&lds[Bb + bro + (nf + 2) * 1024 + k0o];
      b1f[nf * 2 + 1] = *(const short8_t*)&lds[Bb + bro + (nf + 2) * 1024 + k1o];
    }
    __builtin_amdgcn_sched_barrier(0);
    __builtin_amdgcn_s_barrier();
    asm volatile("s_waitcnt lgkmcnt(0)" ::: "memory");
    __builtin_amdgcn_sched_barrier(0);
    __builtin_amdgcn_s_setprio(1);
#pragma unroll
    for (int mf = 0; mf < 4; ++mf)
#pragma unroll
      for (int nf = 0; nf < 2; ++nf) {
        acc[mf][nf+2] = __builtin_amdgcn_mfma_f32_16x16x32_bf16(af[mf*2],   b1f[nf*2],   acc[mf][nf+2], 0, 0, 0);
        acc[mf][nf+2] = __builtin_amdgcn_mfma_f32_16x16x32_bf16(af[mf*2+1], b1f[nf*2+1], acc[mf][nf+2], 0, 0, 0);
      }
    __builtin_amdgcn_s_setprio(0);
    // -------- P2: read A1 (overwrite af), stage A-lo(u+2); MFMA (m1, n2/n3)
#pragma unroll
    for (int mf = 0; mf < 4; ++mf) {
      af[mf * 2]     = *(const short8_t*)&lds[Bb + aro + 4096 + mf * 1024 + k0o];
      af[mf * 2 + 1] = *(const short8_t*)&lds[Bb + aro + 4096 + mf * 1024 + k1o];
    }
    if (u + 2 < NT) SA_LO(u + 2);
    __builtin_amdgcn_sched_barrier(0);
    __builtin_amdgcn_s_barrier();
    asm volatile("s_waitcnt lgkmcnt(0)" ::: "memory");
    __builtin_amdgcn_sched_barrier(0);
    __builtin_amdgcn_s_setprio(1);
#pragma unroll
    for (int mf = 0; mf < 4; ++mf)
#pragma unroll
      for (int nf = 0; nf < 2; ++nf) {
        acc[4+mf][nf+2] = __builtin_amdgcn_mfma_f32_16x16x32_bf16(af[mf*2],   b1f[nf*2],   acc[4+mf][nf+2], 0, 0, 0);
        acc[4+mf][nf+2] = __builtin_amdgcn_mfma_f32_16x16x32_bf16(af[mf*2+1], b1f[nf*2+1], acc[4+mf][nf+2], 0, 0, 0);
      }
    __builtin_amdgcn_s_setprio(0);
    // -------- P3: stage B-lo/hi(u+2); counted vmcnt; MFMA (m1, n0/n1)
    if (u + 2 < NT) {
      SB_LO(u + 2); SB_HI(u + 2);
      asm volatile("s_waitcnt vmcnt(6)" ::: "memory");
    } else {
      asm volatile("s_waitcnt vmcnt(0)" ::: "memory");
    }
    __builtin_amdgcn_sched_barrier(0);
    __builtin_amdgcn_s_barrier();
    asm volatile("s_waitcnt lgkmcnt(0)" ::: "memory");
    __builtin_amdgcn_sched_barrier(0);
    __builtin_amdgcn_s_setprio(1);
#pragma unroll
    for (int mf = 0; mf < 4; ++mf)
#pragma unroll
      for (int nf = 0; nf < 2; ++nf) {
        acc[4+mf][nf] = __builtin_amdgcn_mfma_f32_16x16x32_bf16(af[mf*2],   b0f[nf*2],   acc[4+mf][nf], 0, 0, 0);
        acc[4+mf][nf] = __builtin_amdgcn_mfma_f32_16x16x32_bf16(af[mf*2+1], b0f[nf*2+1], acc[4+mf][nf], 0, 0, 0);
      }
    __builtin_amdgcn_s_setprio(0);
  }
#undef SA_LO
#undef SA_HI
#undef SB_LO
#undef SB_HI

#pragma unroll
  for (int mf = 0; mf < 8; ++mf) {
#pragma unroll
    for (int nf = 0; nf < 4; ++nf) {
      const int col = n0 + wn + nf * 16 + lc;
      const float bv = bias[col];
#pragma unroll
      for (int r = 0; r < 4; ++r) {
        const int row = m0 + wm + mf * 16 + lr * 4 + r;
        C[(size_t)row * N + col] = f2bf(acc[mf][nf][r] + bv);
      }
    }
  }
}

// fused QKV: 384 blocks = 16 m-tiles x (3 mats x 8 n-tiles).  XCD swizzle:
// XCD k owns 3 fixed B-panels (3 MB -> L2-resident) and walks mt 0..15 in
// lockstep with the other XCDs.
__global__ __launch_bounds__(512, 2)
void gemm_qkv(const short* __restrict__ A,
              const short* __restrict__ W0, const short* __restrict__ W1, const short* __restrict__ W2,
              const float* __restrict__ b0, const float* __restrict__ b1, const float* __restrict__ b2,
              short* __restrict__ C0, short* __restrict__ C1, short* __restrict__ C2) {
  const int f   = blockIdx.y * 24 + blockIdx.x;   // dispatch-linear
  const int xcd = f & 7, s = f >> 3;              // s in 0..47
  const int xt  = xcd * 3 + (s >> 4);             // 3 xt per XCD
  const int mt  = s & 15;
  const int sel = xt >> 3, nt = xt & 7;
  const short* Bm   = sel == 0 ? W0 : (sel == 1 ? W1 : W2);
  const float* bias = sel == 0 ? b0 : (sel == 1 ? b1 : b2);
  short* C          = sel == 0 ? C0 : (sel == 1 ? C1 : C2);
  gemm256(A, Bm, bias, C, mt * 256, nt * 256, H_, H_);
}

// ---------------------------------------------------------------- GEMM core v2 (R1, kept for gemm_out)
template<int MODE>
__device__ __forceinline__
void gemm_body256(const short* __restrict__ A, const short* __restrict__ Bm,
                  const float* __restrict__ bias, void* __restrict__ C,
                  const int m0, const int n0, const int N, const int K) {
  extern __shared__ short lds[];
  short* As = lds;            // 4 x 8192 shorts
  short* Bs = lds + 32768;    // 4 x 4096 shorts

  const int tid = threadIdx.x;
  const int w  = tid >> 6, ln = tid & 63;
  const int lr = ln >> 4,  lc = ln & 15;
  const int wm = (w >> 1) << 6;   // 0,64,128,192
  const int wn = (w & 1) << 6;    // 0,64

  const int srr = ln >> 2;
  const int sgc = (ln & 3) ^ ((ln >> 3) & 3);

  const short* aSrc0 = A  + (size_t)(m0 + (w * 2 + 0) * 16 + srr) * K + sgc * 8;
  const short* aSrc1 = A  + (size_t)(m0 + (w * 2 + 1) * 16 + srr) * K + sgc * 8;
  const short* bSrc  = Bm + (size_t)(n0 +  w * 16          + srr) * K + sgc * 8;

  const int aDst0 = (w * 2 + 0) * 512;
  const int aDst1 = (w * 2 + 1) * 512;
  const int bDst  =  w * 512;

#define STAGE_(t_) do {                                      \
    const int bq_ = (t_) & 3; const int ko_ = (t_) * 32;     \
    gload_lds16(aSrc0 + ko_, &As[bq_ * 8192 + aDst0]);       \
    gload_lds16(aSrc1 + ko_, &As[bq_ * 8192 + aDst1]);       \
    gload_lds16(bSrc  + ko_, &Bs[bq_ * 4096 + bDst]);        \
  } while (0)

  STAGE_(0); STAGE_(1); STAGE_(2);

  floatx4 acc[4][4] = {};
  const int swz = (lr ^ ((lc >> 1) & 3)) << 3;
  const int aro = (wm + lc) * 32 + swz;
  const int bro = (wn + lc) * 32 + swz;

  asm volatile("s_waitcnt vmcnt(6)" ::: "memory");
  __builtin_amdgcn_s_barrier();

  const int NT = K >> 5;
  for (int t = 0; t < NT; ++t) {
    const int cb = t & 3;
    short8_t af[4], bfr[4];
#pragma unroll
    for (int i = 0; i < 4; ++i)
      af[i] = *(const short8_t*)&As[cb * 8192 + aro + i * 512];
#pragma unroll
    for (int j = 0; j < 4; ++j)
      bfr[j] = *(const short8_t*)&Bs[cb * 4096 + bro + j * 512];

    if (t + 3 < NT) STAGE_(t + 3);

    __builtin_amdgcn_s_barrier();
    asm volatile("s_waitcnt lgkmcnt(0)" ::: "memory");
    __builtin_amdgcn_sched_barrier(0);
    __builtin_amdgcn_s_setprio(1);
#pragma unroll
    for (int i = 0; i < 4; ++i)
#pragma unroll
      for (int j = 0; j < 4; ++j)
        acc[i][j] = __builtin_amdgcn_mfma_f32_16x16x32_bf16(af[i], bfr[j], acc[i][j], 0, 0, 0);
    __builtin_amdgcn_s_setprio(0);
    __builtin_amdgcn_sched_barrier(0);
    if (t < NT - 3)       asm volatile("s_waitcnt vmcnt(6)" ::: "memory");
    else if (t == NT - 3) asm volatile("s_waitcnt vmcnt(3)" ::: "memory");
    else if (t == NT - 2) asm volatile("s_waitcnt vmcnt(0)" ::: "memory");
    __builtin_amdgcn_s_barrier();
  }
#undef STAGE_

#pragma unroll
  for (int i = 0; i < 4; ++i) {
#pragma unroll
    for (int j = 0; j < 4; ++j) {
      const int col = n0 + wn + j * 16 + lc;
      const float bv = bias[col];
#pragma unroll
      for (int r = 0; r < 4; ++r) {
        const int row = m0 + wm + i * 16 + lr * 4 + r;
        const float v = acc[i][j][r] + bv;
        if (MODE == 1) ((float*)C)[(size_t)row * N + col] = v;
        else           ((short*)C)[(size_t)row * N + col] = f2bf(v);
      }
    }
  }
}

// grid (16, 16) = 256 blocks = 1 exact round
__global__ __launch_bounds__(512, 2)
void gemm_out(const short* __restrict__ A, const short* __restrict__ Bm,
              const float* __restrict__ bias, float* __restrict__ C) {
  gemm_body256<1>(A, Bm, bias, C, blockIdx.y * 256, blockIdx.x * 128, H_, H_);
}

// ---------------------------------------------------------------- V arrange (R5/R7-verified):
// row-major V[b*S+s][h*128+d] -> Vt[bh][kt][d][chunk c'=keychunk^(d&7)]
__global__ __launch_bounds__(256)
void arrange_v(const short* __restrict__ V, short* __restrict__ Vt) {
  __shared__ short T[64][72];
  const int b = blockIdx.z;
  const int s0 = blockIdx.x * 64, c0 = blockIdx.y * 64;
  const int t = threadIdx.x;
  const int r = t >> 3, c8 = (t & 7) * 8;
  const int kt = s0 >> 6;
#pragma unroll
  for (int p = 0; p < 2; ++p) {
    const int row = p * 32 + r;
    *(short8_t*)&T[row][c8] =
        *(const short8_t*)&V[(size_t)(b * S_ + s0 + row) * H_ + c0 + c8];
  }
  __syncthreads();
#pragma unroll
  for (int p = 0; p < 2; ++p) {
    const int row = p * 32 + r;
    const int gcol = c0 + row;
    const int hh = gcol >> 7, d = gcol & 127;
    short8_t o;
#pragma unroll
    for (int j = 0; j < 8; ++j) o[j] = T[c8 + j][row];
    const int chunk = (c8 >> 3) ^ (d & 7);
    *(short8_t*)&Vt[((((size_t)(b * 16 + hh) * 32 + kt) * 128 + d) << 6) + chunk * 8] = o;
  }
}

// ---------------------------------------------------------------- flash attention
// NEW R5: 8 waves/block, 256 q-rows/block, 256 blocks (1/CU), head-grouped
// 1-D grid (bh = bid & 31 -> the 8 q-blocks of a head share an XCD; each XCD
// holds 4 heads' K/V = 4 MB ~ L2).  Per-wave math identical to the verified
// 4-wave version; only the staging slices changed (each wave stages 8 K-rows
// + 1/8 of V = 4 gloads/tile).  K/V staged once per 256 q-rows (was 128) ->
// staging traffic and barrier-drain count per unit work halve.
__global__ __launch_bounds__(512, 1)
void attention(const short* __restrict__ Q, const short* __restrict__ Kg,
               const short* __restrict__ Vt, short* __restrict__ O) {
  __shared__ short Ks[2][64 * 128];   // [key][c' = dchunk ^ (key&7)]
  __shared__ short Vs[2][128 * 64];   // [d][c' = keychunk ^ (d&7)]
  __shared__ float invLds[256];

  const int tid = threadIdx.x;
  const int wv = tid >> 6, ln = tid & 63;
  const int l32 = ln & 31, lh = ln >> 5;
  const int bh = blockIdx.x & 31, b = bh >> 4, h = bh & 15;
  const int qw = (blockIdx.x >> 5) * 256 + wv * 32;

  const short* Qp  = Q  + ((size_t)(b * S_ + qw)) * H_ + h * HD_;
  const short* VtB = Vt + (size_t)bh * (S_ * HD_) + (size_t)wv * 1024 + ln * 8;

  // K staging: wave wv stages keys wv*8..wv*8+7, 2 instrs of 4 rows
  const short* kp[2];
#pragma unroll
  for (int j = 0; j < 2; ++j) {
    const int key = wv * 8 + j * 4 + (ln >> 4);
    const int sc = (ln & 15) ^ (key & 7);
    kp[j] = Kg + (size_t)(b * S_ + key) * H_ + h * HD_ + sc * 8;
  }

  // Q B-frags: lane n=q=l32, k(d) = ksq*16 + lh*8 + j
  short8_t qf[8];
#pragma unroll
  for (int ksq = 0; ksq < 8; ++ksq)
    qf[ksq] = *(const short8_t*)&Qp[(size_t)l32 * H_ + ksq * 16 + lh * 8];

  floatx16 oacc[4] = {};
  float lsum = 0.f;
  const float csc = 0.08838834764831845f * 1.4426950408889634f;

  // prologue: stage tile 0 into buffer 0
#pragma unroll
  for (int j = 0; j < 2; ++j)
    gload_lds16(kp[j], &Ks[0][(wv * 8 + j * 4) * 128]);
#pragma unroll
  for (int j = 0; j < 2; ++j)
    gload_lds16(VtB + j * 512, &Vs[0][wv * 1024 + j * 512]);

  for (int kt = 0; kt < S_ / 64; ++kt) {
    const int cur = kt & 1;
    __syncthreads();   // stage kt landed; all waves done with buf cur^1

    if (kt + 1 < S_ / 64) {
      const size_t kadv = (size_t)(kt + 1) * 64 * H_;
#pragma unroll
      for (int j = 0; j < 2; ++j)
        gload_lds16(kp[j] + kadv, &Ks[cur ^ 1][(wv * 8 + j * 4) * 128]);
#pragma unroll
      for (int j = 0; j < 2; ++j)
        gload_lds16(VtB + (size_t)(kt + 1) * 8192 + j * 512, &Vs[cur ^ 1][wv * 1024 + j * 512]);
    }

    // S^T = K Q^T : C[m=key][n=q]
    floatx16 sacc[2] = {};
#pragma unroll
    for (int kh = 0; kh < 2; ++kh) {
      const int key = kh * 32 + l32;
      const int swk = (key & 7) * 8;
#pragma unroll
      for (int ksq = 0; ksq < 8; ++ksq) {
        const short8_t kf =
            *(const short8_t*)&Ks[cur][key * 128 + (((ksq * 2 + lh) * 8) ^ swk)];
        sacc[kh] = __builtin_amdgcn_mfma_f32_32x32x16_bf16(kf, qf[ksq], sacc[kh], 0, 0, 0);
      }
    }

    // fixed-scale softmax + bf16 pack + in-register transpose to P A-frags
    int pfr[4][4];
#pragma unroll
    for (int kh = 0; kh < 2; ++kh) {
      uint32_t P[8];
#pragma unroll
      for (int i = 0; i < 8; ++i) {
        const uint32_t u0 = __float_as_uint(exp2f(sacc[kh][2 * i] * csc));
        const uint32_t u1 = __float_as_uint(exp2f(sacc[kh][2 * i + 1] * csc));
        lsum += __uint_as_float(u0 & 0xffff0000u) + __uint_as_float(u1 & 0xffff0000u);
        P[i] = (u0 >> 16) | (u1 & 0xffff0000u);
      }
#pragma unroll
      for (int t = 0; t < 2; ++t)
#pragma unroll
        for (int j = 0; j < 2; ++j) {
          const int a = (int)P[t * 4 + j], bb = (int)P[t * 4 + j + 2];
          const int as = __shfl_xor(a, 32), bs = __shfl_xor(bb, 32);
          pfr[kh * 2 + t][j]     = lh ? bs : a;
          pfr[kh * 2 + t][j + 2] = lh ? bb : as;
        }
    }

    // O += P V
#pragma unroll
    for (int kf = 0; kf < 4; ++kf) {
      union { int i[4]; short8_t s; } pu;
#pragma unroll
      for (int j = 0; j < 4; ++j) pu.i[j] = pfr[kf][j];
#pragma unroll
      for (int dt = 0; dt < 4; ++dt) {
        const int d = dt * 32 + l32;
        const short8_t vf =
            *(const short8_t*)&Vs[cur][d * 64 + (((kf * 2 + lh) * 8) ^ ((d & 7) * 8))];
        oacc[dt] = __builtin_amdgcn_mfma_f32_32x32x16_bf16(pu.s, vf, oacc[dt], 0, 0, 0);
      }
    }
  }

  const float l = lsum + __shfl_xor(lsum, 32);
  invLds[wv * 32 + l32] = 1.0f / l;
  float inv[16];
#pragma unroll
  for (int r = 0; r < 16; ++r)
    inv[r] = invLds[wv * 32 + (r & 3) + 8 * (r >> 2) + 4 * lh];
  short* Op = O + ((size_t)(b * S_ + qw)) * H_ + h * HD_;
#pragma unroll
  for (int dt = 0; dt < 4; ++dt)
#pragma unroll
    for (int r = 0; r < 16; ++r) {
      const int rowl = (r & 3) + 8 * (r >> 2) + 4 * lh;
      Op[(size_t)rowl * H_ + dt * 32 + l32] = f2bf(oacc[dt][r] * inv[r]);
    }
}

// ---------------------------------------------------------------- launch
extern "C" void kernel_launch(void* const* d_in, const int* in_sizes, int n_in,
                              void* d_out, int out_size, void* d_ws, size_t ws_size,
                              hipStream_t stream) {
  const float* hidden = (const float*)d_in[0];
  const float* Wq = (const float*)d_in[1];
  const float* bq = (const float*)d_in[2];
  const float* Wk = (const float*)d_in[3];
  const float* bk = (const float*)d_in[4];
  const float* Wv = (const float*)d_in[5];
  const float* bv = (const float*)d_in[6];
  const float* Wo = (const float*)d_in[7];
  const float* bo = (const float*)d_in[8];
  float* out = (float*)d_out;

  char* ws = (char*)d_ws;
  short* hB  = (short*)(ws);                       // 16 MB
  short* WqB = (short*)(ws + (16u << 20));         //  8 MB each
  short* WkB = (short*)(ws + (24u << 20));
  short* WvB = (short*)(ws + (32u << 20));
  short* WoB = (short*)(ws + (40u << 20));
  short* Qb  = (short*)(ws + (48u << 20));         // 16 MB each
  short* Kb  = (short*)(ws + (64u << 20));         // K row-major
  short* Vb  = (short*)(ws + (80u << 20));         // V row-major
  short* Vtb = (short*)(ws + (96u << 20));         // V arranged
  short* Ob  = (short*)(ws + (112u << 20));

  constexpr int QKV_LDS = 2 * 2 * 16384 * 2;            // 128 KiB
  constexpr int OUT_LDS = (4 * 8192 + 4 * 4096) * 2;    // 96 KiB
  static int lds_set = 0;
  if (!lds_set) {
    lds_set = 1;
    (void)hipFuncSetAttribute((const void*)gemm_qkv,
        hipFuncAttributeMaxDynamicSharedMemorySize, QKV_LDS);
    (void)hipFuncSetAttribute((const void*)gemm_out,
        hipFuncAttributeMaxDynamicSharedMemorySize, OUT_LDS);
  }

  cast_all<<<12288, 256, 0, stream>>>(hidden, Wq, Wk, Wv, Wo, hB, WqB, WkB, WvB, WoB);

  gemm_qkv<<<dim3(24, 16), 512, QKV_LDS, stream>>>(hB, WqB, WkB, WvB, bq, bk, bv, Qb, Kb, Vb);

  arrange_v<<<dim3(S_ / 64, H_ / 64, B_), 256, 0, stream>>>(Vb, Vtb);

  attention<<<dim3(S_ / 256 * B_ * NH_), 512, 0, stream>>>(Qb, Kb, Vtb, Ob);

  gemm_out<<<dim3(16, 16), 512, OUT_LDS, stream>>>(Ob, WoB, bo, out);
}

// Round 6
// 393.971 us; speedup vs baseline: 1.0093x; 1.0050x over previous
//
#include <hip/hip_runtime.h>
#include <hip/hip_bf16.h>
#include <stdint.h>

#define B_ 2
#define S_ 2048
#define H_ 2048
#define NH_ 16
#define HD_ 128
#define M_ (B_*S_)

typedef __attribute__((ext_vector_type(8))) short short8_t;
typedef __attribute__((ext_vector_type(4))) float floatx4;
typedef __attribute__((ext_vector_type(16))) float floatx16;

__device__ __forceinline__ short f2bf(float f) {
  union { float f; uint32_t u; } x; x.f = f;
  const uint32_t u = x.u;
  return (short)((u + 0x7FFFu + ((u >> 16) & 1u)) >> 16);   // RNE
}

__device__ __forceinline__ float exp2_fast(float x) {
  float r;
  asm("v_exp_f32 %0, %1" : "=v"(r) : "v"(x));   // native, no libm guards
  return r;
}

__device__ __forceinline__ void gload_lds16(const void* g, void* l) {
  __builtin_amdgcn_global_load_lds(
      (const __attribute__((address_space(1))) void*)g,
      (__attribute__((address_space(3))) void*)l, 16, 0, 0);
}

// ---------------------------------------------------------------- fused casts
__global__ __launch_bounds__(256)
void cast_all(const float* __restrict__ h,  const float* __restrict__ wq,
              const float* __restrict__ wk, const float* __restrict__ wv,
              const float* __restrict__ wo,
              short* __restrict__ hB,  short* __restrict__ wqB,
              short* __restrict__ wkB, short* __restrict__ wvB,
              short* __restrict__ woB) {
  const int blk = blockIdx.x;
  const float* src; short* dst; int off;
  if      (blk <  4096) { src = h;  dst = hB;  off = blk; }
  else if (blk <  6144) { src = wq; dst = wqB; off = blk - 4096; }
  else if (blk <  8192) { src = wk; dst = wkB; off = blk - 6144; }
  else if (blk < 10240) { src = wv; dst = wvB; off = blk - 8192; }
  else                  { src = wo; dst = woB; off = blk - 10240; }
  const int i = (off * 256 + threadIdx.x) * 8;
  typedef __attribute__((ext_vector_type(4))) float f4;
  const f4 a = *(const f4*)(src + i);
  const f4 b = *(const f4*)(src + i + 4);
  short8_t o;
  o[0] = f2bf(a[0]); o[1] = f2bf(a[1]); o[2] = f2bf(a[2]); o[3] = f2bf(a[3]);
  o[4] = f2bf(b[0]); o[5] = f2bf(b[1]); o[6] = f2bf(b[2]); o[7] = f2bf(b[3]);
  *(short8_t*)(dst + i) = o;
}

// ---------------------------------------------------------------- GEMM 256x256, 4 phases/K-tile, ONE barrier/phase
// (R3 winner, 111.6 us, frozen.)  8 waves (2M x 4N) of 128x64 output.
// BK=64, double-buffered 128 KiB LDS.  One barrier per phase (before MFMA).
// Hazard ledger: see R3 notes.  vmcnt(6) before barrier-P3(u); tail vmcnt(0).
__device__ __forceinline__
void gemm256(const short* __restrict__ A, const short* __restrict__ Bm,
             const float* __restrict__ bias, short* __restrict__ C,
             const int m0, const int n0, const int N, const int K) {
  extern __shared__ short lds[];
  const int tid = threadIdx.x;
  const int w  = tid >> 6, ln = tid & 63;
  const int lr = ln >> 4,  lc = ln & 15;
  const int wm = (w >> 2) << 7;   // 0,128
  const int wn = (w & 3) << 6;    // 0,64,128,192

  const int srow = ln >> 3;                 // 0..7
  const int schk = (ln & 7) ^ srow;         // pre-swizzled global chunk
  const short* aS = A  + (size_t)(m0 + w * 16 + srow) * K + schk * 8;
  const short* bS = Bm + (size_t)(n0 + w * 16 + srow) * K + schk * 8;
  const int dA = (w * 16) * 64;             // wave's dest rows (shorts)

#define SA_LO(u_) do { const int q_ = ((u_) & 1) * 32768;                    \
    gload_lds16(aS + (u_) * 64,                    &lds[q_ + dA]);           \
    gload_lds16(aS + (u_) * 64 + (size_t)8 * K,    &lds[q_ + dA + 512]); } while (0)
#define SA_HI(u_) do { const int q_ = ((u_) & 1) * 32768;                    \
    gload_lds16(aS + (u_) * 64 + (size_t)128 * K,  &lds[q_ + 8192 + dA]);    \
    gload_lds16(aS + (u_) * 64 + (size_t)136 * K,  &lds[q_ + 8192 + dA + 512]); } while (0)
#define SB_LO(u_) do { const int q_ = ((u_) & 1) * 32768;                    \
    gload_lds16(bS + (u_) * 64,                    &lds[q_ + 16384 + dA]);   \
    gload_lds16(bS + (u_) * 64 + (size_t)8 * K,    &lds[q_ + 16384 + dA + 512]); } while (0)
#define SB_HI(u_) do { const int q_ = ((u_) & 1) * 32768;                    \
    gload_lds16(bS + (u_) * 64 + (size_t)128 * K,  &lds[q_ + 24576 + dA]);   \
    gload_lds16(bS + (u_) * 64 + (size_t)136 * K,  &lds[q_ + 24576 + dA + 512]); } while (0)

  const int fsw = (lc & 7) << 3;
  const int k0o = (lr * 8) ^ fsw;
  const int k1o = (32 + lr * 8) ^ fsw;
  const int aro = (wm + lc) * 64;           // + half*4096 + mf*1024
  const int bro = 16384 + (wn + lc) * 64;   // + nf*1024

  floatx4 acc[8][4] = {};
  short8_t af[8], b0f[4], b1f[4];

  const int NT = K >> 6;   // 32
  SA_LO(0); SA_HI(0); SB_LO(0); SB_HI(0);
  SA_LO(1); SB_LO(1); SB_HI(1);
  asm volatile("s_waitcnt vmcnt(6)" ::: "memory");   // tile0 landed
  __builtin_amdgcn_s_barrier();

  for (int u = 0; u < NT; ++u) {
    const int Bb = (u & 1) * 32768;
    // -------- P0: read A0 + B0, stage A-hi(u+1); MFMA (m0, n0/n1)
#pragma unroll
    for (int mf = 0; mf < 4; ++mf) {
      af[mf * 2]     = *(const short8_t*)&lds[Bb + aro + mf * 1024 + k0o];
      af[mf * 2 + 1] = *(const short8_t*)&lds[Bb + aro + mf * 1024 + k1o];
    }
#pragma unroll
    for (int nf = 0; nf < 2; ++nf) {
      b0f[nf * 2]     = *(const short8_t*)&lds[Bb + bro + nf * 1024 + k0o];
      b0f[nf * 2 + 1] = *(const short8_t*)&lds[Bb + bro + nf * 1024 + k1o];
    }
    if (u + 1 < NT) SA_HI(u + 1);
    __builtin_amdgcn_sched_barrier(0);
    __builtin_amdgcn_s_barrier();
    asm volatile("s_waitcnt lgkmcnt(0)" ::: "memory");
    __builtin_amdgcn_sched_barrier(0);
    __builtin_amdgcn_s_setprio(1);
#pragma unroll
    for (int mf = 0; mf < 4; ++mf)
#pragma unroll
      for (int nf = 0; nf < 2; ++nf) {
        acc[mf][nf] = __builtin_amdgcn_mfma_f32_16x16x32_bf16(af[mf*2],   b0f[nf*2],   acc[mf][nf], 0, 0, 0);
        acc[mf][nf] = __builtin_amdgcn_mfma_f32_16x16x32_bf16(af[mf*2+1], b0f[nf*2+1], acc[mf][nf], 0, 0, 0);
      }
    __builtin_amdgcn_s_setprio(0);
    // -------- P1: read B1; MFMA (m0, n2/n3)
#pragma unroll
    for (int nf = 0; nf < 2; ++nf) {
      b1f[nf * 2]     = *(const short8_t*)&lds[Bb + bro + (nf + 2) * 1024 + k0o];
      b1f[nf * 2 + 1] = *(const short8_t*)&lds[Bb + bro + (nf + 2) * 1024 + k1o];
    }
    __builtin_amdgcn_sched_barrier(0);
    __builtin_amdgcn_s_barrier();
    asm volatile("s_waitcnt lgkmcnt(0)" ::: "memory");
    __builtin_amdgcn_sched_barrier(0);
    __builtin_amdgcn_s_setprio(1);
#pragma unroll
    for (int mf = 0; mf < 4; ++mf)
#pragma unroll
      for (int nf = 0; nf < 2; ++nf) {
        acc[mf][nf+2] = __builtin_amdgcn_mfma_f32_16x16x32_bf16(af[mf*2],   b1f[nf*2],   acc[mf][nf+2], 0, 0, 0);
        acc[mf][nf+2] = __builtin_amdgcn_mfma_f32_16x16x32_bf16(af[mf*2+1], b1f[nf*2+1], acc[mf][nf+2], 0, 0, 0);
      }
    __builtin_amdgcn_s_setprio(0);
    // -------- P2: read A1 (overwrite af), stage A-lo(u+2); MFMA (m1, n2/n3)
#pragma unroll
    for (int mf = 0; mf < 4; ++mf) {
      af[mf * 2]     = *(const short8_t*)&lds[Bb + aro + 4096 + mf * 1024 + k0o];
      af[mf * 2 + 1] = *(const short8_t*)&lds[Bb + aro + 4096 + mf * 1024 + k1o];
    }
    if (u + 2 < NT) SA_LO(u + 2);
    __builtin_amdgcn_sched_barrier(0);
    __builtin_amdgcn_s_barrier();
    asm volatile("s_waitcnt lgkmcnt(0)" ::: "memory");
    __builtin_amdgcn_sched_barrier(0);
    __builtin_amdgcn_s_setprio(1);
#pragma unroll
    for (int mf = 0; mf < 4; ++mf)
#pragma unroll
      for (int nf = 0; nf < 2; ++nf) {
        acc[4+mf][nf+2] = __builtin_amdgcn_mfma_f32_16x16x32_bf16(af[mf*2],   b1f[nf*2],   acc[4+mf][nf+2], 0, 0, 0);
        acc[4+mf][nf+2] = __builtin_amdgcn_mfma_f32_16x16x32_bf16(af[mf*2+1], b1f[nf*2+1], acc[4+mf][nf+2], 0, 0, 0);
      }
    __builtin_amdgcn_s_setprio(0);
    // -------- P3: stage B-lo/hi(u+2); counted vmcnt; MFMA (m1, n0/n1)
    if (u + 2 < NT) {
      SB_LO(u + 2); SB_HI(u + 2);
      asm volatile("s_waitcnt vmcnt(6)" ::: "memory");
    } else {
      asm volatile("s_waitcnt vmcnt(0)" ::: "memory");
    }
    __builtin_amdgcn_sched_barrier(0);
    __builtin_amdgcn_s_barrier();
    asm volatile("s_waitcnt lgkmcnt(0)" ::: "memory");
    __builtin_amdgcn_sched_barrier(0);
    __builtin_amdgcn_s_setprio(1);
#pragma unroll
    for (int mf = 0; mf < 4; ++mf)
#pragma unroll
      for (int nf = 0; nf < 2; ++nf) {
        acc[4+mf][nf] = __builtin_amdgcn_mfma_f32_16x16x32_bf16(af[mf*2],   b0f[nf*2],   acc[4+mf][nf], 0, 0, 0);
        acc[4+mf][nf] = __builtin_amdgcn_mfma_f32_16x16x32_bf16(af[mf*2+1], b0f[nf*2+1], acc[4+mf][nf], 0, 0, 0);
      }
    __builtin_amdgcn_s_setprio(0);
  }
#undef SA_LO
#undef SA_HI
#undef SB_LO
#undef SB_HI

#pragma unroll
  for (int mf = 0; mf < 8; ++mf) {
#pragma unroll
    for (int nf = 0; nf < 4; ++nf) {
      const int col = n0 + wn + nf * 16 + lc;
      const float bv = bias[col];
#pragma unroll
      for (int r = 0; r < 4; ++r) {
        const int row = m0 + wm + mf * 16 + lr * 4 + r;
        C[(size_t)row * N + col] = f2bf(acc[mf][nf][r] + bv);
      }
    }
  }
}

// fused QKV: 384 blocks = 16 m-tiles x (3 mats x 8 n-tiles).  XCD swizzle:
// XCD k owns 3 fixed B-panels (3 MB -> L2-resident) and walks mt 0..15 in
// lockstep with the other XCDs.
__global__ __launch_bounds__(512, 2)
void gemm_qkv(const short* __restrict__ A,
              const short* __restrict__ W0, const short* __restrict__ W1, const short* __restrict__ W2,
              const float* __restrict__ b0, const float* __restrict__ b1, const float* __restrict__ b2,
              short* __restrict__ C0, short* __restrict__ C1, short* __restrict__ C2) {
  const int f   = blockIdx.y * 24 + blockIdx.x;   // dispatch-linear
  const int xcd = f & 7, s = f >> 3;              // s in 0..47
  const int xt  = xcd * 3 + (s >> 4);             // 3 xt per XCD
  const int mt  = s & 15;
  const int sel = xt >> 3, nt = xt & 7;
  const short* Bm   = sel == 0 ? W0 : (sel == 1 ? W1 : W2);
  const float* bias = sel == 0 ? b0 : (sel == 1 ? b1 : b2);
  short* C          = sel == 0 ? C0 : (sel == 1 ? C1 : C2);
  gemm256(A, Bm, bias, C, mt * 256, nt * 256, H_, H_);
}

// ---------------------------------------------------------------- GEMM core v2 (R1, kept for gemm_out)
template<int MODE>
__device__ __forceinline__
void gemm_body256(const short* __restrict__ A, const short* __restrict__ Bm,
                  const float* __restrict__ bias, void* __restrict__ C,
                  const int m0, const int n0, const int N, const int K) {
  extern __shared__ short lds[];
  short* As = lds;            // 4 x 8192 shorts
  short* Bs = lds + 32768;    // 4 x 4096 shorts

  const int tid = threadIdx.x;
  const int w  = tid >> 6, ln = tid & 63;
  const int lr = ln >> 4,  lc = ln & 15;
  const int wm = (w >> 1) << 6;   // 0,64,128,192
  const int wn = (w & 1) << 6;    // 0,64

  const int srr = ln >> 2;
  const int sgc = (ln & 3) ^ ((ln >> 3) & 3);

  const short* aSrc0 = A  + (size_t)(m0 + (w * 2 + 0) * 16 + srr) * K + sgc * 8;
  const short* aSrc1 = A  + (size_t)(m0 + (w * 2 + 1) * 16 + srr) * K + sgc * 8;
  const short* bSrc  = Bm + (size_t)(n0 +  w * 16          + srr) * K + sgc * 8;

  const int aDst0 = (w * 2 + 0) * 512;
  const int aDst1 = (w * 2 + 1) * 512;
  const int bDst  =  w * 512;

#define STAGE_(t_) do {                                      \
    const int bq_ = (t_) & 3; const int ko_ = (t_) * 32;     \
    gload_lds16(aSrc0 + ko_, &As[bq_ * 8192 + aDst0]);       \
    gload_lds16(aSrc1 + ko_, &As[bq_ * 8192 + aDst1]);       \
    gload_lds16(bSrc  + ko_, &Bs[bq_ * 4096 + bDst]);        \
  } while (0)

  STAGE_(0); STAGE_(1); STAGE_(2);

  floatx4 acc[4][4] = {};
  const int swz = (lr ^ ((lc >> 1) & 3)) << 3;
  const int aro = (wm + lc) * 32 + swz;
  const int bro = (wn + lc) * 32 + swz;

  asm volatile("s_waitcnt vmcnt(6)" ::: "memory");
  __builtin_amdgcn_s_barrier();

  const int NT = K >> 5;
  for (int t = 0; t < NT; ++t) {
    const int cb = t & 3;
    short8_t af[4], bfr[4];
#pragma unroll
    for (int i = 0; i < 4; ++i)
      af[i] = *(const short8_t*)&As[cb * 8192 + aro + i * 512];
#pragma unroll
    for (int j = 0; j < 4; ++j)
      bfr[j] = *(const short8_t*)&Bs[cb * 4096 + bro + j * 512];

    if (t + 3 < NT) STAGE_(t + 3);

    __builtin_amdgcn_s_barrier();
    asm volatile("s_waitcnt lgkmcnt(0)" ::: "memory");
    __builtin_amdgcn_sched_barrier(0);
    __builtin_amdgcn_s_setprio(1);
#pragma unroll
    for (int i = 0; i < 4; ++i)
#pragma unroll
      for (int j = 0; j < 4; ++j)
        acc[i][j] = __builtin_amdgcn_mfma_f32_16x16x32_bf16(af[i], bfr[j], acc[i][j], 0, 0, 0);
    __builtin_amdgcn_s_setprio(0);
    __builtin_amdgcn_sched_barrier(0);
    if (t < NT - 3)       asm volatile("s_waitcnt vmcnt(6)" ::: "memory");
    else if (t == NT - 3) asm volatile("s_waitcnt vmcnt(3)" ::: "memory");
    else if (t == NT - 2) asm volatile("s_waitcnt vmcnt(0)" ::: "memory");
    __builtin_amdgcn_s_barrier();
  }
#undef STAGE_

#pragma unroll
  for (int i = 0; i < 4; ++i) {
#pragma unroll
    for (int j = 0; j < 4; ++j) {
      const int col = n0 + wn + j * 16 + lc;
      const float bv = bias[col];
#pragma unroll
      for (int r = 0; r < 4; ++r) {
        const int row = m0 + wm + i * 16 + lr * 4 + r;
        const float v = acc[i][j][r] + bv;
        if (MODE == 1) ((float*)C)[(size_t)row * N + col] = v;
        else           ((short*)C)[(size_t)row * N + col] = f2bf(v);
      }
    }
  }
}

// grid (16, 16) = 256 blocks = 1 exact round
__global__ __launch_bounds__(512, 2)
void gemm_out(const short* __restrict__ A, const short* __restrict__ Bm,
              const float* __restrict__ bias, float* __restrict__ C) {
  gemm_body256<1>(A, Bm, bias, C, blockIdx.y * 256, blockIdx.x * 128, H_, H_);
}

// ---------------------------------------------------------------- V arrange (R5/R7-verified):
// row-major V[b*S+s][h*128+d] -> Vt[bh][kt][d][chunk c'=keychunk^(d&7)]
__global__ __launch_bounds__(256)
void arrange_v(const short* __restrict__ V, short* __restrict__ Vt) {
  __shared__ short T[64][72];
  const int b = blockIdx.z;
  const int s0 = blockIdx.x * 64, c0 = blockIdx.y * 64;
  const int t = threadIdx.x;
  const int r = t >> 3, c8 = (t & 7) * 8;
  const int kt = s0 >> 6;
#pragma unroll
  for (int p = 0; p < 2; ++p) {
    const int row = p * 32 + r;
    *(short8_t*)&T[row][c8] =
        *(const short8_t*)&V[(size_t)(b * S_ + s0 + row) * H_ + c0 + c8];
  }
  __syncthreads();
#pragma unroll
  for (int p = 0; p < 2; ++p) {
    const int row = p * 32 + r;
    const int gcol = c0 + row;
    const int hh = gcol >> 7, d = gcol & 127;
    short8_t o;
#pragma unroll
    for (int j = 0; j < 8; ++j) o[j] = T[c8 + j][row];
    const int chunk = (c8 >> 3) ^ (d & 7);
    *(short8_t*)&Vt[((((size_t)(b * 16 + hh) * 32 + kt) * 128 + d) << 6) + chunk * 8] = o;
  }
}

// ---------------------------------------------------------------- flash attention
// R6: back to the verified 4-wave / 128 q-rows / 2-blocks-per-CU version
// (cross-block MFMA/VALU overlap).  Two changes vs R0: native v_exp_f32
// (drops libm's range/denormal guards from the 32-exp2 critical path) and
// s_setprio(1) around the QK^T and PV MFMA clusters (T5, attn-proven).
__global__ __launch_bounds__(256, 2)
void attention(const short* __restrict__ Q, const short* __restrict__ Kg,
               const short* __restrict__ Vt, short* __restrict__ O) {
  __shared__ short Ks[2][64 * 128];   // [key][c' = dchunk ^ (key&7)]
  __shared__ short Vs[2][128 * 64];   // [d][c' = keychunk ^ (d&7)]
  __shared__ float invLds[128];

  const int tid = threadIdx.x;
  const int wv = tid >> 6, ln = tid & 63;
  const int l32 = ln & 31, lh = ln >> 5;
  const int bh = blockIdx.y, b = bh >> 4, h = bh & 15;
  const int qw = blockIdx.x * 128 + wv * 32;

  const short* Qp  = Q  + ((size_t)(b * S_ + qw)) * H_ + h * HD_;
  const short* VtB = Vt + (size_t)bh * (S_ * HD_) + (size_t)wv * 2048 + ln * 8;

  const short* kp[4];
#pragma unroll
  for (int j = 0; j < 4; ++j) {
    const int key = wv * 16 + j * 4 + (ln >> 4);
    const int sc = (ln & 15) ^ (key & 7);
    kp[j] = Kg + (size_t)(b * S_ + key) * H_ + h * HD_ + sc * 8;
  }

  short8_t qf[8];
#pragma unroll
  for (int ksq = 0; ksq < 8; ++ksq)
    qf[ksq] = *(const short8_t*)&Qp[(size_t)l32 * H_ + ksq * 16 + lh * 8];

  floatx16 oacc[4] = {};
  float lsum = 0.f;
  const float csc = 0.08838834764831845f * 1.4426950408889634f;

#pragma unroll
  for (int j = 0; j < 4; ++j)
    gload_lds16(kp[j], &Ks[0][(wv * 16 + j * 4) * 128]);
#pragma unroll
  for (int j = 0; j < 4; ++j)
    gload_lds16(VtB + j * 512, &Vs[0][wv * 2048 + j * 512]);

  for (int kt = 0; kt < S_ / 64; ++kt) {
    const int cur = kt & 1;
    __syncthreads();   // stage kt landed; all waves done with buf cur^1

    if (kt + 1 < S_ / 64) {
      const size_t kadv = (size_t)(kt + 1) * 64 * H_;
#pragma unroll
      for (int j = 0; j < 4; ++j)
        gload_lds16(kp[j] + kadv, &Ks[cur ^ 1][(wv * 16 + j * 4) * 128]);
#pragma unroll
      for (int j = 0; j < 4; ++j)
        gload_lds16(VtB + (size_t)(kt + 1) * 8192 + j * 512, &Vs[cur ^ 1][wv * 2048 + j * 512]);
    }

    // S^T = K Q^T : C[m=key][n=q]
    floatx16 sacc[2] = {};
    __builtin_amdgcn_s_setprio(1);
#pragma unroll
    for (int kh = 0; kh < 2; ++kh) {
      const int key = kh * 32 + l32;
      const int swk = (key & 7) * 8;
#pragma unroll
      for (int ksq = 0; ksq < 8; ++ksq) {
        const short8_t kf =
            *(const short8_t*)&Ks[cur][key * 128 + (((ksq * 2 + lh) * 8) ^ swk)];
        sacc[kh] = __builtin_amdgcn_mfma_f32_32x32x16_bf16(kf, qf[ksq], sacc[kh], 0, 0, 0);
      }
    }
    __builtin_amdgcn_s_setprio(0);

    // fixed-scale softmax + bf16 pack + in-register transpose to P A-frags
    int pfr[4][4];
#pragma unroll
    for (int kh = 0; kh < 2; ++kh) {
      uint32_t P[8];
#pragma unroll
      for (int i = 0; i < 8; ++i) {
        const uint32_t u0 = __float_as_uint(exp2_fast(sacc[kh][2 * i] * csc));
        const uint32_t u1 = __float_as_uint(exp2_fast(sacc[kh][2 * i + 1] * csc));
        lsum += __uint_as_float(u0 & 0xffff0000u) + __uint_as_float(u1 & 0xffff0000u);
        P[i] = (u0 >> 16) | (u1 & 0xffff0000u);   // bf16 pair, trunc
      }
#pragma unroll
      for (int t = 0; t < 2; ++t)
#pragma unroll
        for (int j = 0; j < 2; ++j) {
          const int a = (int)P[t * 4 + j], bb = (int)P[t * 4 + j + 2];
          const int as = __shfl_xor(a, 32), bs = __shfl_xor(bb, 32);
          pfr[kh * 2 + t][j]     = lh ? bs : a;
          pfr[kh * 2 + t][j + 2] = lh ? bb : as;
        }
    }

    // O += P V
    __builtin_amdgcn_s_setprio(1);
#pragma unroll
    for (int kf = 0; kf < 4; ++kf) {
      union { int i[4]; short8_t s; } pu;
#pragma unroll
      for (int j = 0; j < 4; ++j) pu.i[j] = pfr[kf][j];
#pragma unroll
      for (int dt = 0; dt < 4; ++dt) {
        const int d = dt * 32 + l32;
        const short8_t vf =
            *(const short8_t*)&Vs[cur][d * 64 + (((kf * 2 + lh) * 8) ^ ((d & 7) * 8))];
        oacc[dt] = __builtin_amdgcn_mfma_f32_32x32x16_bf16(pu.s, vf, oacc[dt], 0, 0, 0);
      }
    }
    __builtin_amdgcn_s_setprio(0);
  }

  const float l = lsum + __shfl_xor(lsum, 32);
  invLds[wv * 32 + l32] = 1.0f / l;
  float inv[16];
#pragma unroll
  for (int r = 0; r < 16; ++r)
    inv[r] = invLds[wv * 32 + (r & 3) + 8 * (r >> 2) + 4 * lh];
  short* Op = O + ((size_t)(b * S_ + qw)) * H_ + h * HD_;
#pragma unroll
  for (int dt = 0; dt < 4; ++dt)
#pragma unroll
    for (int r = 0; r < 16; ++r) {
      const int rowl = (r & 3) + 8 * (r >> 2) + 4 * lh;
      Op[(size_t)rowl * H_ + dt * 32 + l32] = f2bf(oacc[dt][r] * inv[r]);
    }
}

// ---------------------------------------------------------------- launch
extern "C" void kernel_launch(void* const* d_in, const int* in_sizes, int n_in,
                              void* d_out, int out_size, void* d_ws, size_t ws_size,
                              hipStream_t stream) {
  const float* hidden = (const float*)d_in[0];
  const float* Wq = (const float*)d_in[1];
  const float* bq = (const float*)d_in[2];
  const float* Wk = (const float*)d_in[3];
  const float* bk = (const float*)d_in[4];
  const float* Wv = (const float*)d_in[5];
  const float* bv = (const float*)d_in[6];
  const float* Wo = (const float*)d_in[7];
  const float* bo = (const float*)d_in[8];
  float* out = (float*)d_out;

  char* ws = (char*)d_ws;
  short* hB  = (short*)(ws);                       // 16 MB
  short* WqB = (short*)(ws + (16u << 20));         //  8 MB each
  short* WkB = (short*)(ws + (24u << 20));
  short* WvB = (short*)(ws + (32u << 20));
  short* WoB = (short*)(ws + (40u << 20));
  short* Qb  = (short*)(ws + (48u << 20));         // 16 MB each
  short* Kb  = (short*)(ws + (64u << 20));         // K row-major
  short* Vb  = (short*)(ws + (80u << 20));         // V row-major
  short* Vtb = (short*)(ws + (96u << 20));         // V arranged
  short* Ob  = (short*)(ws + (112u << 20));

  constexpr int QKV_LDS = 2 * 2 * 16384 * 2;            // 128 KiB
  constexpr int OUT_LDS = (4 * 8192 + 4 * 4096) * 2;    // 96 KiB
  static int lds_set = 0;
  if (!lds_set) {
    lds_set = 1;
    (void)hipFuncSetAttribute((const void*)gemm_qkv,
        hipFuncAttributeMaxDynamicSharedMemorySize, QKV_LDS);
    (void)hipFuncSetAttribute((const void*)gemm_out,
        hipFuncAttributeMaxDynamicSharedMemorySize, OUT_LDS);
  }

  cast_all<<<12288, 256, 0, stream>>>(hidden, Wq, Wk, Wv, Wo, hB, WqB, WkB, WvB, WoB);

  gemm_qkv<<<dim3(24, 16), 512, QKV_LDS, stream>>>(hB, WqB, WkB, WvB, bq, bk, bv, Qb, Kb, Vb);

  arrange_v<<<dim3(S_ / 64, H_ / 64, B_), 256, 0, stream>>>(Vb, Vtb);

  attention<<<dim3(S_ / 128, B_ * NH_), 256, 0, stream>>>(Qb, Kb, Vtb, Ob);

  gemm_out<<<dim3(16, 16), 512, OUT_LDS, stream>>>(Ob, WoB, bo, out);
}

// Round 7
// 382.706 us; speedup vs baseline: 1.0390x; 1.0294x over previous
//
#include <hip/hip_runtime.h>
#include <hip/hip_bf16.h>
#include <stdint.h>

#define B_ 2
#define S_ 2048
#define H_ 2048
#define NH_ 16
#define HD_ 128
#define M_ (B_*S_)

typedef __attribute__((ext_vector_type(8))) short short8_t;
typedef __attribute__((ext_vector_type(4))) short short4_t;
typedef __attribute__((ext_vector_type(4))) float floatx4;
typedef __attribute__((ext_vector_type(16))) float floatx16;

__device__ __forceinline__ short f2bf(float f) {
  union { float f; uint32_t u; } x; x.f = f;
  const uint32_t u = x.u;
  return (short)((u + 0x7FFFu + ((u >> 16) & 1u)) >> 16);   // RNE
}

__device__ __forceinline__ float exp2_fast(float x) {
  float r;
  asm("v_exp_f32 %0, %1" : "=v"(r) : "v"(x));   // native, no libm guards
  return r;
}

__device__ __forceinline__ void gload_lds16(const void* g, void* l) {
  __builtin_amdgcn_global_load_lds(
      (const __attribute__((address_space(1))) void*)g,
      (__attribute__((address_space(3))) void*)l, 16, 0, 0);
}

// ---------------------------------------------------------------- fused casts
__global__ __launch_bounds__(256)
void cast_all(const float* __restrict__ h,  const float* __restrict__ wq,
              const float* __restrict__ wk, const float* __restrict__ wv,
              const float* __restrict__ wo,
              short* __restrict__ hB,  short* __restrict__ wqB,
              short* __restrict__ wkB, short* __restrict__ wvB,
              short* __restrict__ woB) {
  const int blk = blockIdx.x;
  const float* src; short* dst; int off;
  if      (blk <  4096) { src = h;  dst = hB;  off = blk; }
  else if (blk <  6144) { src = wq; dst = wqB; off = blk - 4096; }
  else if (blk <  8192) { src = wk; dst = wkB; off = blk - 6144; }
  else if (blk < 10240) { src = wv; dst = wvB; off = blk - 8192; }
  else                  { src = wo; dst = woB; off = blk - 10240; }
  const int i = (off * 256 + threadIdx.x) * 8;
  typedef __attribute__((ext_vector_type(4))) float f4;
  const f4 a = *(const f4*)(src + i);
  const f4 b = *(const f4*)(src + i + 4);
  short8_t o;
  o[0] = f2bf(a[0]); o[1] = f2bf(a[1]); o[2] = f2bf(a[2]); o[3] = f2bf(a[3]);
  o[4] = f2bf(b[0]); o[5] = f2bf(b[1]); o[6] = f2bf(b[2]); o[7] = f2bf(b[3]);
  *(short8_t*)(dst + i) = o;
}

// ---------------------------------------------------------------- GEMM 256x256, 4 phases/K-tile, ONE barrier/phase
// (R3 winner, 111.6 us; loop body frozen.)  8 waves (2M x 4N) of 128x64
// output.  BK=64, double-buffered 128 KiB LDS.  One barrier per phase.
// Hazard ledger: see R3 notes.  vmcnt(6) before barrier-P3(u); tail vmcnt(0).
// NEW R7: epilogue vmode — vmode=1 writes V directly in the arranged
// Vt[bh][kt][d][chunk c'=keychunk^(d&7)] layout (replaces arrange_v; values
// bit-identical since arrange_v only copied bf16).  Rows r=0..3 of an acc
// quad are consecutive keys within one 8-chunk -> short4 store.
__device__ __forceinline__
void gemm256(const short* __restrict__ A, const short* __restrict__ Bm,
             const float* __restrict__ bias, short* __restrict__ C,
             const int m0, const int n0, const int N, const int K,
             const int vmode) {
  extern __shared__ short lds[];
  const int tid = threadIdx.x;
  const int w  = tid >> 6, ln = tid & 63;
  const int lr = ln >> 4,  lc = ln & 15;
  const int wm = (w >> 2) << 7;   // 0,128
  const int wn = (w & 3) << 6;    // 0,64,128,192

  const int srow = ln >> 3;                 // 0..7
  const int schk = (ln & 7) ^ srow;         // pre-swizzled global chunk
  const short* aS = A  + (size_t)(m0 + w * 16 + srow) * K + schk * 8;
  const short* bS = Bm + (size_t)(n0 + w * 16 + srow) * K + schk * 8;
  const int dA = (w * 16) * 64;             // wave's dest rows (shorts)

#define SA_LO(u_) do { const int q_ = ((u_) & 1) * 32768;                    \
    gload_lds16(aS + (u_) * 64,                    &lds[q_ + dA]);           \
    gload_lds16(aS + (u_) * 64 + (size_t)8 * K,    &lds[q_ + dA + 512]); } while (0)
#define SA_HI(u_) do { const int q_ = ((u_) & 1) * 32768;                    \
    gload_lds16(aS + (u_) * 64 + (size_t)128 * K,  &lds[q_ + 8192 + dA]);    \
    gload_lds16(aS + (u_) * 64 + (size_t)136 * K,  &lds[q_ + 8192 + dA + 512]); } while (0)
#define SB_LO(u_) do { const int q_ = ((u_) & 1) * 32768;                    \
    gload_lds16(bS + (u_) * 64,                    &lds[q_ + 16384 + dA]);   \
    gload_lds16(bS + (u_) * 64 + (size_t)8 * K,    &lds[q_ + 16384 + dA + 512]); } while (0)
#define SB_HI(u_) do { const int q_ = ((u_) & 1) * 32768;                    \
    gload_lds16(bS + (u_) * 64 + (size_t)128 * K,  &lds[q_ + 24576 + dA]);   \
    gload_lds16(bS + (u_) * 64 + (size_t)136 * K,  &lds[q_ + 24576 + dA + 512]); } while (0)

  const int fsw = (lc & 7) << 3;
  const int k0o = (lr * 8) ^ fsw;
  const int k1o = (32 + lr * 8) ^ fsw;
  const int aro = (wm + lc) * 64;           // + half*4096 + mf*1024
  const int bro = 16384 + (wn + lc) * 64;   // + nf*1024

  floatx4 acc[8][4] = {};
  short8_t af[8], b0f[4], b1f[4];

  const int NT = K >> 6;   // 32
  SA_LO(0); SA_HI(0); SB_LO(0); SB_HI(0);
  SA_LO(1); SB_LO(1); SB_HI(1);
  asm volatile("s_waitcnt vmcnt(6)" ::: "memory");   // tile0 landed
  __builtin_amdgcn_s_barrier();

  for (int u = 0; u < NT; ++u) {
    const int Bb = (u & 1) * 32768;
    // -------- P0: read A0 + B0, stage A-hi(u+1); MFMA (m0, n0/n1)
#pragma unroll
    for (int mf = 0; mf < 4; ++mf) {
      af[mf * 2]     = *(const short8_t*)&lds[Bb + aro + mf * 1024 + k0o];
      af[mf * 2 + 1] = *(const short8_t*)&lds[Bb + aro + mf * 1024 + k1o];
    }
#pragma unroll
    for (int nf = 0; nf < 2; ++nf) {
      b0f[nf * 2]     = *(const short8_t*)&lds[Bb + bro + nf * 1024 + k0o];
      b0f[nf * 2 + 1] = *(const short8_t*)&lds[Bb + bro + nf * 1024 + k1o];
    }
    if (u + 1 < NT) SA_HI(u + 1);
    __builtin_amdgcn_sched_barrier(0);
    __builtin_amdgcn_s_barrier();
    asm volatile("s_waitcnt lgkmcnt(0)" ::: "memory");
    __builtin_amdgcn_sched_barrier(0);
    __builtin_amdgcn_s_setprio(1);
#pragma unroll
    for (int mf = 0; mf < 4; ++mf)
#pragma unroll
      for (int nf = 0; nf < 2; ++nf) {
        acc[mf][nf] = __builtin_amdgcn_mfma_f32_16x16x32_bf16(af[mf*2],   b0f[nf*2],   acc[mf][nf], 0, 0, 0);
        acc[mf][nf] = __builtin_amdgcn_mfma_f32_16x16x32_bf16(af[mf*2+1], b0f[nf*2+1], acc[mf][nf], 0, 0, 0);
      }
    __builtin_amdgcn_s_setprio(0);
    // -------- P1: read B1; MFMA (m0, n2/n3)
#pragma unroll
    for (int nf = 0; nf < 2; ++nf) {
      b1f[nf * 2]     = *(const short8_t*)&lds[Bb + bro + (nf + 2) * 1024 + k0o];
      b1f[nf * 2 + 1] = *(const short8_t*)&lds[Bb + bro + (nf + 2) * 1024 + k1o];
    }
    __builtin_amdgcn_sched_barrier(0);
    __builtin_amdgcn_s_barrier();
    asm volatile("s_waitcnt lgkmcnt(0)" ::: "memory");
    __builtin_amdgcn_sched_barrier(0);
    __builtin_amdgcn_s_setprio(1);
#pragma unroll
    for (int mf = 0; mf < 4; ++mf)
#pragma unroll
      for (int nf = 0; nf < 2; ++nf) {
        acc[mf][nf+2] = __builtin_amdgcn_mfma_f32_16x16x32_bf16(af[mf*2],   b1f[nf*2],   acc[mf][nf+2], 0, 0, 0);
        acc[mf][nf+2] = __builtin_amdgcn_mfma_f32_16x16x32_bf16(af[mf*2+1], b1f[nf*2+1], acc[mf][nf+2], 0, 0, 0);
      }
    __builtin_amdgcn_s_setprio(0);
    // -------- P2: read A1 (overwrite af), stage A-lo(u+2); MFMA (m1, n2/n3)
#pragma unroll
    for (int mf = 0; mf < 4; ++mf) {
      af[mf * 2]     = *(const short8_t*)&lds[Bb + aro + 4096 + mf * 1024 + k0o];
      af[mf * 2 + 1] = *(const short8_t*)&lds[Bb + aro + 4096 + mf * 1024 + k1o];
    }
    if (u + 2 < NT) SA_LO(u + 2);
    __builtin_amdgcn_sched_barrier(0);
    __builtin_amdgcn_s_barrier();
    asm volatile("s_waitcnt lgkmcnt(0)" ::: "memory");
    __builtin_amdgcn_sched_barrier(0);
    __builtin_amdgcn_s_setprio(1);
#pragma unroll
    for (int mf = 0; mf < 4; ++mf)
#pragma unroll
      for (int nf = 0; nf < 2; ++nf) {
        acc[4+mf][nf+2] = __builtin_amdgcn_mfma_f32_16x16x32_bf16(af[mf*2],   b1f[nf*2],   acc[4+mf][nf+2], 0, 0, 0);
        acc[4+mf][nf+2] = __builtin_amdgcn_mfma_f32_16x16x32_bf16(af[mf*2+1], b1f[nf*2+1], acc[4+mf][nf+2], 0, 0, 0);
      }
    __builtin_amdgcn_s_setprio(0);
    // -------- P3: stage B-lo/hi(u+2); counted vmcnt; MFMA (m1, n0/n1)
    if (u + 2 < NT) {
      SB_LO(u + 2); SB_HI(u + 2);
      asm volatile("s_waitcnt vmcnt(6)" ::: "memory");
    } else {
      asm volatile("s_waitcnt vmcnt(0)" ::: "memory");
    }
    __builtin_amdgcn_sched_barrier(0);
    __builtin_amdgcn_s_barrier();
    asm volatile("s_waitcnt lgkmcnt(0)" ::: "memory");
    __builtin_amdgcn_sched_barrier(0);
    __builtin_amdgcn_s_setprio(1);
#pragma unroll
    for (int mf = 0; mf < 4; ++mf)
#pragma unroll
      for (int nf = 0; nf < 2; ++nf) {
        acc[4+mf][nf] = __builtin_amdgcn_mfma_f32_16x16x32_bf16(af[mf*2],   b0f[nf*2],   acc[4+mf][nf], 0, 0, 0);
        acc[4+mf][nf] = __builtin_amdgcn_mfma_f32_16x16x32_bf16(af[mf*2+1], b0f[nf*2+1], acc[4+mf][nf], 0, 0, 0);
      }
    __builtin_amdgcn_s_setprio(0);
  }
#undef SA_LO
#undef SA_HI
#undef SB_LO
#undef SB_HI

#pragma unroll
  for (int mf = 0; mf < 8; ++mf) {
#pragma unroll
    for (int nf = 0; nf < 4; ++nf) {
      const int col = n0 + wn + nf * 16 + lc;
      const float bv = bias[col];
      if (!vmode) {
#pragma unroll
        for (int r = 0; r < 4; ++r) {
          const int row = m0 + wm + mf * 16 + lr * 4 + r;
          C[(size_t)row * N + col] = f2bf(acc[mf][nf][r] + bv);
        }
      } else {
        // V-direct: row = token (b*S+s), col = h*128+d ->
        // Vt[(((b*16+h)*32 + s>>6)*128 + d)*64 + ((s>>3&7)^(d&7))*8 + (s&7)]
        const int row0 = m0 + wm + mf * 16 + lr * 4;   // 4 consecutive keys
        const int bb = row0 >> 11, s = row0 & (S_ - 1);
        const int hh = col >> 7,  dd = col & 127;
        const size_t base =
            ((((size_t)(bb * 16 + hh) * 32 + (s >> 6)) * 128 + dd) << 6)
            + (((((s >> 3) & 7) << 3) ^ ((dd & 7) << 3)) + (s & 7));
        short4_t v4;
        v4[0] = f2bf(acc[mf][nf][0] + bv);
        v4[1] = f2bf(acc[mf][nf][1] + bv);
        v4[2] = f2bf(acc[mf][nf][2] + bv);
        v4[3] = f2bf(acc[mf][nf][3] + bv);
        *(short4_t*)&C[base] = v4;
      }
    }
  }
}

// fused QKV: 384 blocks = 16 m-tiles x (3 mats x 8 n-tiles).  XCD swizzle:
// XCD k owns 3 fixed B-panels (3 MB -> L2-resident) and walks mt 0..15 in
// lockstep with the other XCDs.  sel==2 writes V directly in Vt layout.
__global__ __launch_bounds__(512, 2)
void gemm_qkv(const short* __restrict__ A,
              const short* __restrict__ W0, const short* __restrict__ W1, const short* __restrict__ W2,
              const float* __restrict__ b0, const float* __restrict__ b1, const float* __restrict__ b2,
              short* __restrict__ C0, short* __restrict__ C1, short* __restrict__ C2) {
  const int f   = blockIdx.y * 24 + blockIdx.x;   // dispatch-linear
  const int xcd = f & 7, s = f >> 3;              // s in 0..47
  const int xt  = xcd * 3 + (s >> 4);             // 3 xt per XCD
  const int mt  = s & 15;
  const int sel = xt >> 3, nt = xt & 7;
  const short* Bm   = sel == 0 ? W0 : (sel == 1 ? W1 : W2);
  const float* bias = sel == 0 ? b0 : (sel == 1 ? b1 : b2);
  short* C          = sel == 0 ? C0 : (sel == 1 ? C1 : C2);
  gemm256(A, Bm, bias, C, mt * 256, nt * 256, H_, H_, sel == 2 ? 1 : 0);
}

// ---------------------------------------------------------------- GEMM core (gemm_out)
// R1 256x128 / BK=32 / 4-slot ring, NOW one-barrier-per-K-step (R3-proven
// conversion): counted vmcnt BEFORE the single barrier (retires stage(t+1)
// cross-wave); no post-MFMA barrier, so a finished wave issues reads(t+1)/
// stage(t+4) while slower waves still MFMA.  Slot-overwrite margin: stage
// DMA lands >=200cy after issue, trailing reads retired ~120cy after the
// shared barrier (same ledger style as the R3 qkv loop).
template<int MODE>
__device__ __forceinline__
void gemm_body256(const short* __restrict__ A, const short* __restrict__ Bm,
                  const float* __restrict__ bias, void* __restrict__ C,
                  const int m0, const int n0, const int N, const int K) {
  extern __shared__ short lds[];
  short* As = lds;            // 4 x 8192 shorts
  short* Bs = lds + 32768;    // 4 x 4096 shorts

  const int tid = threadIdx.x;
  const int w  = tid >> 6, ln = tid & 63;
  const int lr = ln >> 4,  lc = ln & 15;
  const int wm = (w >> 1) << 6;   // 0,64,128,192
  const int wn = (w & 1) << 6;    // 0,64

  const int srr = ln >> 2;
  const int sgc = (ln & 3) ^ ((ln >> 3) & 3);

  const short* aSrc0 = A  + (size_t)(m0 + (w * 2 + 0) * 16 + srr) * K + sgc * 8;
  const short* aSrc1 = A  + (size_t)(m0 + (w * 2 + 1) * 16 + srr) * K + sgc * 8;
  const short* bSrc  = Bm + (size_t)(n0 +  w * 16          + srr) * K + sgc * 8;

  const int aDst0 = (w * 2 + 0) * 512;
  const int aDst1 = (w * 2 + 1) * 512;
  const int bDst  =  w * 512;

#define STAGE_(t_) do {                                      \
    const int bq_ = (t_) & 3; const int ko_ = (t_) * 32;     \
    gload_lds16(aSrc0 + ko_, &As[bq_ * 8192 + aDst0]);       \
    gload_lds16(aSrc1 + ko_, &As[bq_ * 8192 + aDst1]);       \
    gload_lds16(bSrc  + ko_, &Bs[bq_ * 4096 + bDst]);        \
  } while (0)

  STAGE_(0); STAGE_(1); STAGE_(2);

  floatx4 acc[4][4] = {};
  const int swz = (lr ^ ((lc >> 1) & 3)) << 3;
  const int aro = (wm + lc) * 32 + swz;
  const int bro = (wn + lc) * 32 + swz;

  asm volatile("s_waitcnt vmcnt(6)" ::: "memory");
  __builtin_amdgcn_s_barrier();

  const int NT = K >> 5;
  for (int t = 0; t < NT; ++t) {
    const int cb = t & 3;
    short8_t af[4], bfr[4];
#pragma unroll
    for (int i = 0; i < 4; ++i)
      af[i] = *(const short8_t*)&As[cb * 8192 + aro + i * 512];
#pragma unroll
    for (int j = 0; j < 4; ++j)
      bfr[j] = *(const short8_t*)&Bs[cb * 4096 + bro + j * 512];

    if (t + 3 < NT) STAGE_(t + 3);

    if (t < NT - 3)       asm volatile("s_waitcnt vmcnt(6)" ::: "memory");
    else if (t == NT - 3) asm volatile("s_waitcnt vmcnt(3)" ::: "memory");
    else                  asm volatile("s_waitcnt vmcnt(0)" ::: "memory");
    __builtin_amdgcn_sched_barrier(0);
    __builtin_amdgcn_s_barrier();
    asm volatile("s_waitcnt lgkmcnt(0)" ::: "memory");
    __builtin_amdgcn_sched_barrier(0);
    __builtin_amdgcn_s_setprio(1);
#pragma unroll
    for (int i = 0; i < 4; ++i)
#pragma unroll
      for (int j = 0; j < 4; ++j)
        acc[i][j] = __builtin_amdgcn_mfma_f32_16x16x32_bf16(af[i], bfr[j], acc[i][j], 0, 0, 0);
    __builtin_amdgcn_s_setprio(0);
  }
#undef STAGE_

#pragma unroll
  for (int i = 0; i < 4; ++i) {
#pragma unroll
    for (int j = 0; j < 4; ++j) {
      const int col = n0 + wn + j * 16 + lc;
      const float bv = bias[col];
#pragma unroll
      for (int r = 0; r < 4; ++r) {
        const int row = m0 + wm + i * 16 + lr * 4 + r;
        const float v = acc[i][j][r] + bv;
        if (MODE == 1) ((float*)C)[(size_t)row * N + col] = v;
        else           ((short*)C)[(size_t)row * N + col] = f2bf(v);
      }
    }
  }
}

// grid (16, 16) = 256 blocks = 1 exact round
__global__ __launch_bounds__(512, 2)
void gemm_out(const short* __restrict__ A, const short* __restrict__ Bm,
              const float* __restrict__ bias, float* __restrict__ C) {
  gemm_body256<1>(A, Bm, bias, C, blockIdx.y * 256, blockIdx.x * 128, H_, H_);
}

// ---------------------------------------------------------------- flash attention
// 4-wave / 128 q-rows / 2 blocks-per-CU (verified).  Swapped QK^T, in-reg
// P transpose, fixed-scale softmax, native v_exp_f32, setprio around MFMA
// clusters, double-buffered K/V via global_load_lds.
__global__ __launch_bounds__(256, 2)
void attention(const short* __restrict__ Q, const short* __restrict__ Kg,
               const short* __restrict__ Vt, short* __restrict__ O) {
  __shared__ short Ks[2][64 * 128];   // [key][c' = dchunk ^ (key&7)]
  __shared__ short Vs[2][128 * 64];   // [d][c' = keychunk ^ (d&7)]
  __shared__ float invLds[128];

  const int tid = threadIdx.x;
  const int wv = tid >> 6, ln = tid & 63;
  const int l32 = ln & 31, lh = ln >> 5;
  const int bh = blockIdx.y, b = bh >> 4, h = bh & 15;
  const int qw = blockIdx.x * 128 + wv * 32;

  const short* Qp  = Q  + ((size_t)(b * S_ + qw)) * H_ + h * HD_;
  const short* VtB = Vt + (size_t)bh * (S_ * HD_) + (size_t)wv * 2048 + ln * 8;

  const short* kp[4];
#pragma unroll
  for (int j = 0; j < 4; ++j) {
    const int key = wv * 16 + j * 4 + (ln >> 4);
    const int sc = (ln & 15) ^ (key & 7);
    kp[j] = Kg + (size_t)(b * S_ + key) * H_ + h * HD_ + sc * 8;
  }

  short8_t qf[8];
#pragma unroll
  for (int ksq = 0; ksq < 8; ++ksq)
    qf[ksq] = *(const short8_t*)&Qp[(size_t)l32 * H_ + ksq * 16 + lh * 8];

  floatx16 oacc[4] = {};
  float lsum = 0.f;
  const float csc = 0.08838834764831845f * 1.4426950408889634f;

#pragma unroll
  for (int j = 0; j < 4; ++j)
    gload_lds16(kp[j], &Ks[0][(wv * 16 + j * 4) * 128]);
#pragma unroll
  for (int j = 0; j < 4; ++j)
    gload_lds16(VtB + j * 512, &Vs[0][wv * 2048 + j * 512]);

  for (int kt = 0; kt < S_ / 64; ++kt) {
    const int cur = kt & 1;
    __syncthreads();   // stage kt landed; all waves done with buf cur^1

    if (kt + 1 < S_ / 64) {
      const size_t kadv = (size_t)(kt + 1) * 64 * H_;
#pragma unroll
      for (int j = 0; j < 4; ++j)
        gload_lds16(kp[j] + kadv, &Ks[cur ^ 1][(wv * 16 + j * 4) * 128]);
#pragma unroll
      for (int j = 0; j < 4; ++j)
        gload_lds16(VtB + (size_t)(kt + 1) * 8192 + j * 512, &Vs[cur ^ 1][wv * 2048 + j * 512]);
    }

    // S^T = K Q^T : C[m=key][n=q]
    floatx16 sacc[2] = {};
    __builtin_amdgcn_s_setprio(1);
#pragma unroll
    for (int kh = 0; kh < 2; ++kh) {
      const int key = kh * 32 + l32;
      const int swk = (key & 7) * 8;
#pragma unroll
      for (int ksq = 0; ksq < 8; ++ksq) {
        const short8_t kf =
            *(const short8_t*)&Ks[cur][key * 128 + (((ksq * 2 + lh) * 8) ^ swk)];
        sacc[kh] = __builtin_amdgcn_mfma_f32_32x32x16_bf16(kf, qf[ksq], sacc[kh], 0, 0, 0);
      }
    }
    __builtin_amdgcn_s_setprio(0);

    // fixed-scale softmax + bf16 pack + in-register transpose to P A-frags
    int pfr[4][4];
#pragma unroll
    for (int kh = 0; kh < 2; ++kh) {
      uint32_t P[8];
#pragma unroll
      for (int i = 0; i < 8; ++i) {
        const uint32_t u0 = __float_as_uint(exp2_fast(sacc[kh][2 * i] * csc));
        const uint32_t u1 = __float_as_uint(exp2_fast(sacc[kh][2 * i + 1] * csc));
        lsum += __uint_as_float(u0 & 0xffff0000u) + __uint_as_float(u1 & 0xffff0000u);
        P[i] = (u0 >> 16) | (u1 & 0xffff0000u);   // bf16 pair, trunc
      }
#pragma unroll
      for (int t = 0; t < 2; ++t)
#pragma unroll
        for (int j = 0; j < 2; ++j) {
          const int a = (int)P[t * 4 + j], bb = (int)P[t * 4 + j + 2];
          const int as = __shfl_xor(a, 32), bs = __shfl_xor(bb, 32);
          pfr[kh * 2 + t][j]     = lh ? bs : a;
          pfr[kh * 2 + t][j + 2] = lh ? bb : as;
        }
    }

    // O += P V
    __builtin_amdgcn_s_setprio(1);
#pragma unroll
    for (int kf = 0; kf < 4; ++kf) {
      union { int i[4]; short8_t s; } pu;
#pragma unroll
      for (int j = 0; j < 4; ++j) pu.i[j] = pfr[kf][j];
#pragma unroll
      for (int dt = 0; dt < 4; ++dt) {
        const int d = dt * 32 + l32;
        const short8_t vf =
            *(const short8_t*)&Vs[cur][d * 64 + (((kf * 2 + lh) * 8) ^ ((d & 7) * 8))];
        oacc[dt] = __builtin_amdgcn_mfma_f32_32x32x16_bf16(pu.s, vf, oacc[dt], 0, 0, 0);
      }
    }
    __builtin_amdgcn_s_setprio(0);
  }

  const float l = lsum + __shfl_xor(lsum, 32);
  invLds[wv * 32 + l32] = 1.0f / l;
  float inv[16];
#pragma unroll
  for (int r = 0; r < 16; ++r)
    inv[r] = invLds[wv * 32 + (r & 3) + 8 * (r >> 2) + 4 * lh];
  short* Op = O + ((size_t)(b * S_ + qw)) * H_ + h * HD_;
#pragma unroll
  for (int dt = 0; dt < 4; ++dt)
#pragma unroll
    for (int r = 0; r < 16; ++r) {
      const int rowl = (r & 3) + 8 * (r >> 2) + 4 * lh;
      Op[(size_t)rowl * H_ + dt * 32 + l32] = f2bf(oacc[dt][r] * inv[r]);
    }
}

// ---------------------------------------------------------------- launch
extern "C" void kernel_launch(void* const* d_in, const int* in_sizes, int n_in,
                              void* d_out, int out_size, void* d_ws, size_t ws_size,
                              hipStream_t stream) {
  const float* hidden = (const float*)d_in[0];
  const float* Wq = (const float*)d_in[1];
  const float* bq = (const float*)d_in[2];
  const float* Wk = (const float*)d_in[3];
  const float* bk = (const float*)d_in[4];
  const float* Wv = (const float*)d_in[5];
  const float* bv = (const float*)d_in[6];
  const float* Wo = (const float*)d_in[7];
  const float* bo = (const float*)d_in[8];
  float* out = (float*)d_out;

  char* ws = (char*)d_ws;
  short* hB  = (short*)(ws);                       // 16 MB
  short* WqB = (short*)(ws + (16u << 20));         //  8 MB each
  short* WkB = (short*)(ws + (24u << 20));
  short* WvB = (short*)(ws + (32u << 20));
  short* WoB = (short*)(ws + (40u << 20));
  short* Qb  = (short*)(ws + (48u << 20));         // 16 MB each
  short* Kb  = (short*)(ws + (64u << 20));         // K row-major
  short* Vtb = (short*)(ws + (96u << 20));         // V arranged (written by gemm_qkv)
  short* Ob  = (short*)(ws + (112u << 20));

  constexpr int QKV_LDS = 2 * 2 * 16384 * 2;            // 128 KiB
  constexpr int OUT_LDS = (4 * 8192 + 4 * 4096) * 2;    // 96 KiB
  static int lds_set = 0;
  if (!lds_set) {
    lds_set = 1;
    (void)hipFuncSetAttribute((const void*)gemm_qkv,
        hipFuncAttributeMaxDynamicSharedMemorySize, QKV_LDS);
    (void)hipFuncSetAttribute((const void*)gemm_out,
        hipFuncAttributeMaxDynamicSharedMemorySize, OUT_LDS);
  }

  cast_all<<<12288, 256, 0, stream>>>(hidden, Wq, Wk, Wv, Wo, hB, WqB, WkB, WvB, WoB);

  gemm_qkv<<<dim3(24, 16), 512, QKV_LDS, stream>>>(hB, WqB, WkB, WvB, bq, bk, bv, Qb, Kb, Vtb);

  attention<<<dim3(S_ / 128, B_ * NH_), 256, 0, stream>>>(Qb, Kb, Vtb, Ob);

  gemm_out<<<dim3(16, 16), 512, OUT_LDS, stream>>>(Ob, WoB, bo, out);
}